// Round 6
// baseline (157.187 us; speedup 1.0000x reference)
//
#include <hip/hip_runtime.h>

#define DEV __device__ __forceinline__

typedef int v4i __attribute__((ext_vector_type(4)));
typedef short v8s __attribute__((ext_vector_type(8)));
typedef float v4f __attribute__((ext_vector_type(4)));

// quantize pre-scaled y3 = 3*y: clamp to [0,3], round-to-even
DEV unsigned int quant3(float y3) {
    return (unsigned int)(int)rintf(fminf(fmaxf(y3, 0.f), 3.f));
}

DEV int imax(int a, int b) { return a > b ? a : b; }
DEV int imin(int a, int b) { return a < b ? a : b; }

// float -> bf16 bits, round-to-nearest-even (x never NaN here)
DEV unsigned short f2bf(float x) {
    union { float f; unsigned u; } v; v.f = x;
    unsigned r = v.u + 0x7fffu + ((v.u >> 16) & 1u);
    return (unsigned short)(r >> 16);
}
DEV float bf2f(unsigned short b) {
    union { unsigned u; float f; } v; v.u = (unsigned)b << 16;
    return v.f;
}

// ---------------------------------------------------------------------------
// Sign precompute: w2/w3 [co][ci][3][3] -> s8 [co][t][ci] (t=ky*3+kx), fw1 -> s8
// ---------------------------------------------------------------------------
__global__ __launch_bounds__(256) void k_signs(
    const float* __restrict__ w2, const float* __restrict__ w3,
    const float* __restrict__ fw1,
    char* __restrict__ w2s, char* __restrict__ w3s, char* __restrict__ fw1s) {
    int i = blockIdx.x * 256 + threadIdx.x;
    if (i < 36864) {
        int co = i / 576, r = i - co * 576;
        int ci = r / 9, k = r - ci * 9;
        w2s[co * 576 + k * 64 + ci] = (w2[i] >= 0.f) ? 1 : -1;
        w3s[co * 576 + k * 64 + ci] = (w3[i] >= 0.f) ? 1 : -1;
    }
    if (i < 819200) fw1s[i] = (fw1[i] >= 0.f) ? 1 : -1;
}

// ---------------------------------------------------------------------------
// conv1 via bf16 MFMA, exact 3-split (x = hi+mid+lo, each bf16-exact).
// GEOMETRY (fixed): 28x28 conv pixels = 196 pool quads = 784 im2col rows
// = 49 M-tiles of 16 (exact, no clamping). Quad-mapped M-rows: quad
// s = tile*4 + (r>>2), member (r&3) = (dy,dx); C row m = lg*4+reg -> each
// lane's 4 acc f32 = one 2x2 pool window -> pool = 3 fmax in-register.
// K = 9 taps x 3 splits = 27 (pad 32). A rows stride 80B (2-way = free).
// Wave w owns N-tile w (channels w*16..+15), loops all 49 M-tiles.
// ---------------------------------------------------------------------------
__global__ __launch_bounds__(256, 2) void k_conv1_mfma(
    const float* __restrict__ x, const float* __restrict__ w1f,
    const float* __restrict__ b1, unsigned char* __restrict__ a1) {
    __shared__ float sxp[30][30];     // zero-padded image
    __shared__ uint4 sAu[3920];       // 784 rows * 80B
    __shared__ uint4 sBu[320];        // 64 rows * 80B
    __shared__ float sb3[64];
    unsigned char* sAb = (unsigned char*)sAu;
    unsigned char* sBb = (unsigned char*)sBu;
    int b = blockIdx.x, tid = threadIdx.x;

    // phase 1 (disjoint writes): border zeros, x interior, B build, bias
    if (tid < 116) {
        int py, px;
        if (tid < 30)      { py = 0;  px = tid; }
        else if (tid < 60) { py = 29; px = tid - 30; }
        else if (tid < 88) { py = tid - 59; px = 0; }
        else               { py = tid - 87; px = 29; }
        sxp[py][px] = 0.f;
    }
    for (int i = tid; i < 784; i += 256) {
        int iy = i / 28, ix = i - iy * 28;
        sxp[iy + 1][ix + 1] = x[(size_t)b * 784 + i];
    }
    if (tid < 64) {
        const float* wrow = w1f + tid * 9;
        unsigned short sg[9];
#pragma unroll
        for (int t = 0; t < 9; ++t)
            sg[t] = (wrow[t] >= 0.f) ? (unsigned short)0x3F80 : (unsigned short)0xBF80;
        unsigned int d[16];
#pragma unroll
        for (int i = 0; i < 13; ++i)
            d[i] = (unsigned)sg[(2 * i) / 3] | ((unsigned)sg[(2 * i + 1) / 3] << 16);
        d[13] = (unsigned)sg[8];  // k=26 lo half; k=27 zero
        d[14] = 0; d[15] = 0;
        uint4* dst = (uint4*)(sBb + tid * 80);
        dst[0] = make_uint4(d[0], d[1], d[2], d[3]);
        dst[1] = make_uint4(d[4], d[5], d[6], d[7]);
        dst[2] = make_uint4(d[8], d[9], d[10], d[11]);
        dst[3] = make_uint4(d[12], d[13], d[14], d[15]);
        sb3[tid] = 3.f * b1[tid];
    }
    __syncthreads();

    // phase 2: build im2col A rows (784 rows; row = quad*4 + member)
    for (int row = tid; row < 784; row += 256) {
        int s = row >> 2, r = row & 3;            // quad, member
        int qy = s / 14, qx = s - qy * 14;
        int cy = 2 * qy + (r >> 1);               // conv pixel (padded coords)
        int cx = 2 * qx + (r & 1);
        float p[9];
#pragma unroll
        for (int ky = 0; ky < 3; ++ky)
#pragma unroll
            for (int kx = 0; kx < 3; ++kx)
                p[ky * 3 + kx] = sxp[cy + ky][cx + kx];
        unsigned short hml[28];
#pragma unroll
        for (int t = 0; t < 9; ++t) {
            float xv = p[t];
            unsigned short h = f2bf(xv);
            float r1 = xv - bf2f(h);       // exact
            unsigned short m = f2bf(r1);
            float r2 = r1 - bf2f(m);       // exact
            unsigned short lo = f2bf(r2);
            hml[t * 3 + 0] = h; hml[t * 3 + 1] = m; hml[t * 3 + 2] = lo;
        }
        hml[27] = 0;
        unsigned int d[16];
#pragma unroll
        for (int i = 0; i < 14; ++i)
            d[i] = (unsigned)hml[2 * i] | ((unsigned)hml[2 * i + 1] << 16);
        d[14] = 0; d[15] = 0;
        uint4* dst = (uint4*)(sAb + row * 80);
        dst[0] = make_uint4(d[0], d[1], d[2], d[3]);
        dst[1] = make_uint4(d[4], d[5], d[6], d[7]);
        dst[2] = make_uint4(d[8], d[9], d[10], d[11]);
        dst[3] = make_uint4(d[12], d[13], d[14], d[15]);
    }
    __syncthreads();

    // phase 3: MFMA. wave w -> N-tile w; loop 49 M-tiles.
    int w = tid >> 6, l = tid & 63;
    int lr = l & 15, lg = l >> 4;
    v8s bfrag = *(const v8s*)(sBb + (w * 16 + lr) * 80 + lg * 16);
    float myb3 = sb3[w * 16 + lr];
    unsigned char* outp = a1 + (size_t)b * 12544 + w * 16 + lr;
    for (int mt = 0; mt < 49; ++mt) {
        v8s af = *(const v8s*)(sAb + (mt * 16 + lr) * 80 + lg * 16);
        v4f acc = {0.f, 0.f, 0.f, 0.f};
        acc = __builtin_amdgcn_mfma_f32_16x16x32_bf16(af, bfrag, acc, 0, 0, 0);
        int q = mt * 4 + lg;                      // pool pixel 0..195
        float mx = fmaxf(fmaxf(acc[0], acc[1]), fmaxf(acc[2], acc[3]));
        outp[q * 64] = (unsigned char)quant3(fmaf(mx, 3.f, myb3));
    }
}

// ---------------------------------------------------------------------------
// conv2 via i8 MFMA, QUAD-MAPPED M-rows (round-4 version, unchanged)
// ---------------------------------------------------------------------------
__global__ __launch_bounds__(256, 3) void k_conv2_mfma(
    const unsigned char* __restrict__ a1, const char* __restrict__ w2s,
    const float* __restrict__ g1, const float* __restrict__ be1,
    const float* __restrict__ m1, const float* __restrict__ v1,
    unsigned char* __restrict__ a2) {
    __shared__ unsigned char sa[16384];      // [ck][16x16 padded pix][16]
    __shared__ char sw[36864];               // [t][ck][64 co][16]
    __shared__ float ssc[64], sof[64];
    int b = blockIdx.x, tid = threadIdx.x;
    if (tid < 240) {
        int ck = tid & 3, e = tid >> 2;
        int py, px;
        if (e < 16)      { py = 0;      px = e; }
        else if (e < 32) { py = 15;     px = e - 16; }
        else if (e < 46) { py = e - 31; px = 0; }
        else             { py = e - 45; px = 15; }
        *(uint4*)(sa + ck * 4096 + (py * 16 + px) * 16) = make_uint4(0, 0, 0, 0);
    }
    {
        const uint4* src = (const uint4*)(a1 + (size_t)b * 12544);
        for (int i = tid; i < 784; i += 256) {
            int pixel = i >> 2, ck = i & 3;
            int py = pixel / 14, px = pixel - py * 14;
            *(uint4*)(sa + ck * 4096 + ((py + 1) * 16 + px + 1) * 16) = src[i];
        }
        for (int u = tid; u < 2304; u += 256) {
            int co = u / 36, rem = u - co * 36;
            int t = rem >> 2, ck = rem & 3;
            *(uint4*)(sw + t * 4096 + ck * 1024 + co * 16) =
                *(const uint4*)(w2s + co * 576 + t * 64 + ck * 16);
        }
        if (tid < 64) {
            float si = g1[tid] * rsqrtf(v1[tid] + 1e-4f);
            ssc[tid] = si;
            sof[tid] = 3.f * (be1[tid] - m1[tid] * si);
        }
    }
    __syncthreads();

    int w = tid >> 6, l = tid & 63;
    int lr = l & 15, lg = l >> 4;
    int abase[4], mts[4];
#pragma unroll
    for (int j = 0; j < 4; ++j) {
        int mt = w + 4 * j;
        mts[j] = mt;
        int s = mt * 4 + (lr >> 2);
        if (s > 48) s = 48;
        int qy = s / 7, qx = s - qy * 7;
        int ty = 2 * qy + ((lr >> 1) & 1);
        int tx = 2 * qx + (lr & 1);
        abase[j] = lg * 4096 + (ty * 16 + tx) * 16;
    }
    v4i acc[4][4] = {};
#pragma unroll
    for (int t = 0; t < 9; ++t) {
        int ky = t / 3, kx = t - ky * 3;
        int boff = t * 4096 + lg * 1024 + lr * 16;
        v4i bf[4];
#pragma unroll
        for (int nt = 0; nt < 4; ++nt)
            bf[nt] = *(const v4i*)(sw + boff + nt * 256);
        int aoff = (ky * 16 + kx) * 16;
#pragma unroll
        for (int j = 0; j < 4; ++j) {
            if (mts[j] < 13) {
                v4i af = *(const v4i*)(sa + abase[j] + aoff);
#pragma unroll
                for (int nt = 0; nt < 4; ++nt)
                    acc[j][nt] = __builtin_amdgcn_mfma_i32_16x16x64_i8(
                        af, bf[nt], acc[j][nt], 0, 0, 0);
            }
        }
    }

#pragma unroll
    for (int j = 0; j < 4; ++j) {
        int q = mts[j] * 4 + lg;
        if (q < 49) {
            unsigned char* outp = a2 + (size_t)b * 3136 + q * 64;
#pragma unroll
            for (int nt = 0; nt < 4; ++nt) {
                int ch = nt * 16 + lr;
                int mx = imax(imax(acc[j][nt][0], acc[j][nt][1]),
                              imax(acc[j][nt][2], acc[j][nt][3]));
                int mn = imin(imin(acc[j][nt][0], acc[j][nt][1]),
                              imin(acc[j][nt][2], acc[j][nt][3]));
                float sc = ssc[ch];
                int v = (sc >= 0.f) ? mx : mn;
                outp[ch] = (unsigned char)quant3(fmaf((float)v, sc, sof[ch]));
            }
        }
    }
}

// ---------------------------------------------------------------------------
// conv3 via i8 MFMA: 4 images per block (unchanged)
// ---------------------------------------------------------------------------
__global__ __launch_bounds__(256) void k_conv3_mfma(
    const unsigned char* __restrict__ a2, const char* __restrict__ w3s,
    const float* __restrict__ g2, const float* __restrict__ be2,
    const float* __restrict__ m2, const float* __restrict__ v2,
    unsigned char* __restrict__ a3) {
    __shared__ unsigned char sa[4 * 3136];
    __shared__ char sw[36864];
    __shared__ unsigned char so[4 * 2560];
    __shared__ float ssc[64], sof[64];
    int b0 = blockIdx.x * 4, tid = threadIdx.x;
    {
        const uint4* src = (const uint4*)(a2 + (size_t)b0 * 3136);
        for (int i = tid; i < 784; i += 256) {
            int img = i / 196, r = i - img * 196;
            int pixel = r >> 2, ck = r & 3;
            *(uint4*)(sa + img * 3136 + ck * 784 + pixel * 16) = src[i];
        }
        for (int u = tid; u < 2304; u += 256) {
            int co = u / 36, rem = u - co * 36;
            int t = rem >> 2, ck = rem & 3;
            *(uint4*)(sw + t * 4096 + ck * 1024 + co * 16) =
                *(const uint4*)(w3s + co * 576 + t * 64 + ck * 16);
        }
        if (tid < 64) {
            float si = g2[tid] * rsqrtf(v2[tid] + 1e-4f);
            ssc[tid] = si;
            sof[tid] = 3.f * (be2[tid] - m2[tid] * si);
        }
    }
    __syncthreads();

    int w = tid >> 6, l = tid & 63;
    int lr = l & 15, lg = l >> 4;
    const unsigned char* sai = sa + w * 3136;
    int abase[2];
#pragma unroll
    for (int mt = 0; mt < 2; ++mt) {
        int p = mt * 16 + lr;
        if (p > 24) p = 24;
        int oy = p / 5, ox = p - oy * 5;
        abase[mt] = lg * 784 + (oy * 7 + ox) * 16;
    }
    v4i acc[2][4] = {};
#pragma unroll
    for (int t = 0; t < 9; ++t) {
        int ky = t / 3, kx = t - ky * 3;
        int boff = t * 4096 + lg * 1024 + lr * 16;
        v4i bf[4];
#pragma unroll
        for (int nt = 0; nt < 4; ++nt)
            bf[nt] = *(const v4i*)(sw + boff + nt * 256);
        int aoff = (ky * 7 + kx) * 16;
#pragma unroll
        for (int mt = 0; mt < 2; ++mt) {
            v4i af = *(const v4i*)(sai + abase[mt] + aoff);
#pragma unroll
            for (int nt = 0; nt < 4; ++nt)
                acc[mt][nt] = __builtin_amdgcn_mfma_i32_16x16x64_i8(
                    af, bf[nt], acc[mt][nt], 0, 0, 0);
        }
    }

    unsigned char* soi = so + w * 2560;
#pragma unroll
    for (int mt = 0; mt < 2; ++mt)
#pragma unroll
        for (int nt = 0; nt < 4; ++nt) {
            int ch = nt * 16 + lr;
            float sc = ssc[ch], of = sof[ch];
#pragma unroll
            for (int r = 0; r < 4; ++r) {
                int pixel = mt * 16 + lg * 4 + r;
                soi[pixel * 80 + ch] =
                    (unsigned char)quant3(fmaf((float)acc[mt][nt][r], sc, of));
            }
        }
    __syncthreads();
    for (int idx = tid; idx < 400; idx += 256) {
        int img = idx / 100, r = idx - img * 100;
        int p = r >> 2, c0 = r & 3;
        *(uint4*)(a3 + (size_t)(b0 + img) * 1600 + r * 16) =
            *(const uint4*)(so + img * 2560 + p * 80 + c0 * 16);
    }
}

// ---------------------------------------------------------------------------
// fc1 via i8 MFMA (unchanged)
// ---------------------------------------------------------------------------
__global__ __launch_bounds__(256) void k_fc1_mfma(
    const unsigned char* __restrict__ a3, const char* __restrict__ fw1s,
    const float* __restrict__ fb1, float* __restrict__ h1) {
    __shared__ unsigned char sA[64 * 80];
    __shared__ unsigned char sB[64 * 80];
    __shared__ float sbias[64];
    int bb = (blockIdx.x >> 3) * 64;
    int ob = (blockIdx.x & 7) * 64;
    int tid = threadIdx.x;
    int row = tid >> 2, seg = tid & 3;
    if (tid < 64) sbias[tid] = fb1[ob + tid];
    const unsigned char* Ag = a3 + (size_t)(bb + row) * 1600 + seg * 16;
    const char* Bg = fw1s + (size_t)(ob + row) * 1600 + seg * 16;
    uint4 av = *(const uint4*)Ag;
    uint4 bv = *(const uint4*)Bg;

    int w = tid >> 6, l = tid & 63;
    int wm = w >> 1, wn = w & 1;
    int lr = l & 15, lg = l >> 4;
    const unsigned char* sAr = sA + (wm * 32 + lr) * 80 + lg * 16;
    const unsigned char* sBr = sB + (wn * 32 + lr) * 80 + lg * 16;
    v4i acc[2][2] = {};

    for (int k0 = 0; k0 < 1600; k0 += 64) {
        *(uint4*)(sA + row * 80 + seg * 16) = av;
        *(uint4*)(sB + row * 80 + seg * 16) = bv;
        __syncthreads();
        if (k0 < 1536) {
            av = *(const uint4*)(Ag + k0 + 64);
            bv = *(const uint4*)(Bg + k0 + 64);
        }
        v4i af0 = *(const v4i*)(sAr);
        v4i af1 = *(const v4i*)(sAr + 16 * 80);
        v4i bf0 = *(const v4i*)(sBr);
        v4i bf1 = *(const v4i*)(sBr + 16 * 80);
        acc[0][0] = __builtin_amdgcn_mfma_i32_16x16x64_i8(af0, bf0, acc[0][0], 0, 0, 0);
        acc[0][1] = __builtin_amdgcn_mfma_i32_16x16x64_i8(af0, bf1, acc[0][1], 0, 0, 0);
        acc[1][0] = __builtin_amdgcn_mfma_i32_16x16x64_i8(af1, bf0, acc[1][0], 0, 0, 0);
        acc[1][1] = __builtin_amdgcn_mfma_i32_16x16x64_i8(af1, bf1, acc[1][1], 0, 0, 0);
        __syncthreads();
    }

    const float inv3 = 1.f / 3.f;
#pragma unroll
    for (int mt = 0; mt < 2; ++mt)
#pragma unroll
        for (int nt = 0; nt < 2; ++nt) {
            int gcol = ob + wn * 32 + nt * 16 + lr;
            float bias = sbias[wn * 32 + nt * 16 + lr];
#pragma unroll
            for (int r = 0; r < 4; ++r) {
                int grow = bb + wm * 32 + mt * 16 + lg * 4 + r;
                h1[(size_t)grow * 512 + gcol] = (float)acc[mt][nt][r] * inv3 + bias;
            }
        }
}

// ---------------------------------------------------------------------------
// fc2 + log_softmax (unchanged)
// ---------------------------------------------------------------------------
__global__ __launch_bounds__(256) void k_fc2(
    const float* __restrict__ h1, const float* __restrict__ fw2,
    const float* __restrict__ fb2, float* __restrict__ out) {
    __shared__ float sw[5120];
    __shared__ float sb[16];
    int tid = threadIdx.x;
    for (int i = tid; i < 5120; i += 256) sw[i] = fw2[i];
    if (tid < 10) sb[tid] = fb2[tid];
    __syncthreads();

    int wv = tid >> 6, lane = tid & 63;
    int b = blockIdx.x * 4 + wv;
    const float* hr = h1 + (size_t)b * 512;
    float p[10];
#pragma unroll
    for (int o = 0; o < 10; ++o) p[o] = 0.f;
    for (int k = lane; k < 512; k += 64) {
        float hv = hr[k];
#pragma unroll
        for (int o = 0; o < 10; ++o) p[o] += hv * sw[o * 512 + k];
    }
#pragma unroll
    for (int o = 0; o < 10; ++o) {
#pragma unroll
        for (int off = 32; off > 0; off >>= 1) p[o] += __shfl_xor(p[o], off, 64);
        p[o] += sb[o];
    }
    float mx = p[0];
#pragma unroll
    for (int o = 1; o < 10; ++o) mx = fmaxf(mx, p[o]);
    float se = 0.f;
#pragma unroll
    for (int o = 0; o < 10; ++o) se += expf(p[o] - mx);
    float lse = logf(se) + mx;
    float myv = 0.f;
#pragma unroll
    for (int o = 0; o < 10; ++o) myv = (lane == o) ? p[o] : myv;
    if (lane < 10) out[(size_t)b * 10 + lane] = myv - lse;
}

// ---------------------------------------------------------------------------
extern "C" void kernel_launch(void* const* d_in, const int* in_sizes, int n_in,
                              void* d_out, int out_size, void* d_ws, size_t ws_size,
                              hipStream_t stream) {
    const float* x   = (const float*)d_in[0];
    const float* w1  = (const float*)d_in[1];
    const float* b1  = (const float*)d_in[2];
    const float* w2  = (const float*)d_in[3];
    const float* g1  = (const float*)d_in[4];
    const float* be1 = (const float*)d_in[5];
    const float* m1  = (const float*)d_in[6];
    const float* v1  = (const float*)d_in[7];
    const float* w3  = (const float*)d_in[8];
    const float* g2  = (const float*)d_in[9];
    const float* be2 = (const float*)d_in[10];
    const float* m2  = (const float*)d_in[11];
    const float* v2  = (const float*)d_in[12];
    const float* fw1 = (const float*)d_in[13];
    const float* fb1 = (const float*)d_in[14];
    const float* fw2 = (const float*)d_in[15];
    const float* fb2 = (const float*)d_in[16];
    float* out = (float*)d_out;

    char* ws = (char*)d_ws;
    char* w2s  = ws;                                   // 36864
    char* w3s  = ws + 36864;                           // 36864
    char* fw1s = ws + 73728;                           // 819200
    unsigned char* a1 = (unsigned char*)(ws + 892928); // 4096*12544 = 51380224
    unsigned char* a2 = a1 + 51380224;                 // 4096*3136  = 12845056
    unsigned char* a3 = a2 + 12845056;                 // 4096*1600  = 6553600
    float* h1 = (float*)(void*)a1;                     // alias: a1 dead when fc1 runs

    k_signs<<<3200, 256, 0, stream>>>(w2, w3, fw1, w2s, w3s, fw1s);
    k_conv1_mfma<<<4096, 256, 0, stream>>>(x, w1, b1, a1);
    k_conv2_mfma<<<4096, 256, 0, stream>>>(a1, w2s, g1, be1, m1, v1, a2);
    k_conv3_mfma<<<1024, 256, 0, stream>>>(a2, w3s, g2, be2, m2, v2, a3);
    k_fc1_mfma<<<512, 256, 0, stream>>>(a3, fw1s, fb1, h1);
    k_fc2<<<1024, 256, 0, stream>>>(h1, fw2, fb2, out);
}

// Round 7
// 139.346 us; speedup vs baseline: 1.1280x; 1.1280x over previous
//
#include <hip/hip_runtime.h>

#define DEV __device__ __forceinline__

typedef int v4i __attribute__((ext_vector_type(4)));
typedef short v8s __attribute__((ext_vector_type(8)));
typedef float v4f __attribute__((ext_vector_type(4)));

// quantize pre-scaled y3 = 3*y: clamp to [0,3], round-to-even
DEV unsigned int quant3(float y3) {
    return (unsigned int)(int)rintf(fminf(fmaxf(y3, 0.f), 3.f));
}

DEV int imax(int a, int b) { return a > b ? a : b; }
DEV int imin(int a, int b) { return a < b ? a : b; }

// float -> bf16 bits, round-to-nearest-even (x never NaN here)
DEV unsigned int f2bf(float x) {
    union { float f; unsigned u; } v; v.f = x;
    unsigned r = v.u + 0x7fffu + ((v.u >> 16) & 1u);
    return r >> 16;
}
DEV float bf2f(unsigned int b) {
    union { unsigned u; float f; } v; v.u = b << 16;
    return v.f;
}
// full 3-way exact split
#define SPLIT3(v, H, M, L)                        \
    unsigned int H = f2bf(v);                     \
    float r1_##H = (v) - bf2f(H);                 \
    unsigned int M = f2bf(r1_##H);                \
    unsigned int L = f2bf(r1_##H - bf2f(M));
// partial: hi+mid only
#define SPLIT2(v, H, M)                           \
    unsigned int H = f2bf(v);                     \
    unsigned int M = f2bf((v) - bf2f(H));
// hi only
#define SPLIT1(v, H) unsigned int H = f2bf(v);

// ---------------------------------------------------------------------------
// Sign precompute: w2/w3 [co][ci][3][3] -> s8 [co][t][ci] (t=ky*3+kx), fw1 -> s8
// ---------------------------------------------------------------------------
__global__ __launch_bounds__(256) void k_signs(
    const float* __restrict__ w2, const float* __restrict__ w3,
    const float* __restrict__ fw1,
    char* __restrict__ w2s, char* __restrict__ w3s, char* __restrict__ fw1s) {
    int i = blockIdx.x * 256 + threadIdx.x;
    if (i < 36864) {
        int co = i / 576, r = i - co * 576;
        int ci = r / 9, k = r - ci * 9;
        w2s[co * 576 + k * 64 + ci] = (w2[i] >= 0.f) ? 1 : -1;
        w3s[co * 576 + k * 64 + ci] = (w3[i] >= 0.f) ? 1 : -1;
    }
    if (i < 819200) fw1s[i] = (fw1[i] >= 0.f) ? 1 : -1;
}

// ---------------------------------------------------------------------------
// conv1 via bf16 MFMA, v4:
//  - exact 3-split (x = hi+mid+lo, each bf16-exact); K = 9 taps x 3 = 27 pad 32,
//    tap-major k = t*3+sp.
//  - 196 pool quads -> 784 im2col rows -> 52 M-tiles (49 real + 3 pad) in
//    4 phases x 13 tiles. A-buffer = 13 KB fragment layout [tile][lane][16B]:
//    MFMA read is linear l*16 (conflict-free b128).
//  - build: one 16B slice per thread (<=4 pixel reads + <=4 splits, switch(lg),
//    lg-major slice order => wave-uniform lg, contiguous writes).
//  - M-partitioned: wave w owns tiles mtl = w,w+4,..; B-frags (all 4 N-tiles)
//    in registers => A read ONCE per tile.
//  - quad-mapped rows: lane's 4 acc f32 = one 2x2 pool window -> 3 fmax.
// LDS ~21 KB -> ~5 blocks/CU.
// ---------------------------------------------------------------------------
__global__ __launch_bounds__(256, 4) void k_conv1_mfma(
    const float* __restrict__ x, const float* __restrict__ w1f,
    const float* __restrict__ b1, unsigned char* __restrict__ a1) {
    __shared__ float sxp[30][32];        // zero-padded image (cols 0..29 used)
    __shared__ unsigned char sA[13312];  // 13 tiles * 1024
    __shared__ unsigned char sB[4096];   // 4 nt * 64 lanes * 16
    int b = blockIdx.x, tid = threadIdx.x;

    // ---- stage: border zeros (disjoint from interior), x interior, B build
    if (tid < 116) {
        int py, px;
        if (tid < 30)      { py = 0;  px = tid; }
        else if (tid < 60) { py = 29; px = tid - 30; }
        else if (tid < 88) { py = tid - 59; px = 0; }
        else               { py = tid - 87; px = 29; }
        sxp[py][px] = 0.f;
    }
    for (int i = tid; i < 784; i += 256) {
        int iy = i / 28, ix = i - iy * 28;
        sxp[iy + 1][ix + 1] = x[(size_t)b * 784 + i];
    }
    {   // B slice: thread -> (nt = tid>>6, lane l = tid&63)
        int nt = tid >> 6, bl = tid & 63, blr = bl & 15, blg = bl >> 4;
        const float* wr = w1f + (nt * 16 + blr) * 9;
        unsigned int d[4];
#pragma unroll
        for (int jj = 0; jj < 4; ++jj) {
            int k0 = blg * 8 + jj * 2, k1 = k0 + 1;
            int t0 = (k0 * 21846) >> 16; if (t0 > 8) t0 = 8;
            int t1 = (k1 * 21846) >> 16; if (t1 > 8) t1 = 8;
            unsigned int lo16 = (k0 < 27) ? ((wr[t0] >= 0.f) ? 0x3F80u : 0xBF80u) : 0u;
            unsigned int hi16 = (k1 < 27) ? ((wr[t1] >= 0.f) ? 0x3F80u : 0xBF80u) : 0u;
            d[jj] = lo16 | (hi16 << 16);
        }
        *(uint4*)(sB + tid * 16) = make_uint4(d[0], d[1], d[2], d[3]);
    }
    int l = tid & 63, lr = l & 15, lg = l >> 4, w = tid >> 6;
    float b3[4];
#pragma unroll
    for (int nt = 0; nt < 4; ++nt) b3[nt] = 3.f * b1[nt * 16 + lr];
    __syncthreads();

    v8s bf[4];
#pragma unroll
    for (int nt = 0; nt < 4; ++nt) bf[nt] = *(const v8s*)(sB + nt * 1024 + l * 16);

    unsigned char* outb = a1 + (size_t)b * 12544;

    for (int p = 0; p < 4; ++p) {
        // ---- build 13 tiles (832 slices), lg-major slice order
#pragma unroll
        for (int it = 0; it < 4; ++it) {
            int s = tid + it * 256;
            if (s < 832) {
                int s4 = s >> 4;
                int blg = (s4 * 5042) >> 16;     // /13
                int mtl = s4 - blg * 13;
                int blr = s & 15;
                int mt = p * 13 + mtl;
                int q = mt * 4 + (blr >> 2); if (q > 195) q = 195;
                int qy = (q * 4682) >> 16;       // /14
                int qx = q - qy * 14;
                int cy = 2 * qy + ((blr >> 1) & 1);
                int cx = 2 * qx + (blr & 1);
                const float* p0 = &sxp[cy][cx];
                unsigned int d0, d1, d2, d3;
                if (blg == 0) {
                    float v0 = p0[0], v1 = p0[1], v2 = p0[2];
                    SPLIT3(v0, h0, m0, l0);
                    SPLIT3(v1, h1, m1, l1);
                    SPLIT2(v2, h2, m2);
                    d0 = h0 | (m0 << 16); d1 = l0 | (h1 << 16);
                    d2 = m1 | (l1 << 16); d3 = h2 | (m2 << 16);
                } else if (blg == 1) {
                    float v2 = p0[2], v3 = p0[32], v4 = p0[33], v5 = p0[34];
                    SPLIT3(v2, h2, m2, l2);
                    SPLIT3(v3, h3, m3, l3);
                    SPLIT3(v4, h4, m4, l4);
                    SPLIT1(v5, h5);
                    (void)h2; (void)m2;
                    d0 = l2 | (h3 << 16); d1 = m3 | (l3 << 16);
                    d2 = h4 | (m4 << 16); d3 = l4 | (h5 << 16);
                } else if (blg == 2) {
                    float v5 = p0[34], v6 = p0[64], v7 = p0[65];
                    SPLIT3(v5, h5, m5, l5);
                    SPLIT3(v6, h6, m6, l6);
                    SPLIT3(v7, h7, m7, l7);
                    (void)h5;
                    d0 = m5 | (l5 << 16); d1 = h6 | (m6 << 16);
                    d2 = l6 | (h7 << 16); d3 = m7 | (l7 << 16);
                } else {
                    float v8 = p0[66];
                    SPLIT3(v8, h8, m8, l8);
                    d0 = h8 | (m8 << 16); d1 = l8; d2 = 0; d3 = 0;
                }
                *(uint4*)(sA + mtl * 1024 + (blg * 16 + blr) * 16) =
                    make_uint4(d0, d1, d2, d3);
            }
        }
        __syncthreads();
        // ---- MFMA: wave w -> tiles mtl = w, w+4, w+8, w+12
        for (int mtl = w; mtl < 13; mtl += 4) {
            v8s af = *(const v8s*)(sA + mtl * 1024 + l * 16);
            int q = (p * 13 + mtl) * 4 + lg;
#pragma unroll
            for (int nt = 0; nt < 4; ++nt) {
                v4f acc = {0.f, 0.f, 0.f, 0.f};
                acc = __builtin_amdgcn_mfma_f32_16x16x32_bf16(af, bf[nt], acc, 0, 0, 0);
                if (q < 196) {
                    float mx = fmaxf(fmaxf(acc[0], acc[1]), fmaxf(acc[2], acc[3]));
                    outb[q * 64 + nt * 16 + lr] =
                        (unsigned char)quant3(fmaf(mx, 3.f, b3[nt]));
                }
            }
        }
        __syncthreads();
    }
}

// ---------------------------------------------------------------------------
// conv2 via i8 MFMA, QUAD-MAPPED M-rows (round-4 version, unchanged)
// ---------------------------------------------------------------------------
__global__ __launch_bounds__(256, 3) void k_conv2_mfma(
    const unsigned char* __restrict__ a1, const char* __restrict__ w2s,
    const float* __restrict__ g1, const float* __restrict__ be1,
    const float* __restrict__ m1, const float* __restrict__ v1,
    unsigned char* __restrict__ a2) {
    __shared__ unsigned char sa[16384];      // [ck][16x16 padded pix][16]
    __shared__ char sw[36864];               // [t][ck][64 co][16]
    __shared__ float ssc[64], sof[64];
    int b = blockIdx.x, tid = threadIdx.x;
    if (tid < 240) {
        int ck = tid & 3, e = tid >> 2;
        int py, px;
        if (e < 16)      { py = 0;      px = e; }
        else if (e < 32) { py = 15;     px = e - 16; }
        else if (e < 46) { py = e - 31; px = 0; }
        else             { py = e - 45; px = 15; }
        *(uint4*)(sa + ck * 4096 + (py * 16 + px) * 16) = make_uint4(0, 0, 0, 0);
    }
    {
        const uint4* src = (const uint4*)(a1 + (size_t)b * 12544);
        for (int i = tid; i < 784; i += 256) {
            int pixel = i >> 2, ck = i & 3;
            int py = pixel / 14, px = pixel - py * 14;
            *(uint4*)(sa + ck * 4096 + ((py + 1) * 16 + px + 1) * 16) = src[i];
        }
        for (int u = tid; u < 2304; u += 256) {
            int co = u / 36, rem = u - co * 36;
            int t = rem >> 2, ck = rem & 3;
            *(uint4*)(sw + t * 4096 + ck * 1024 + co * 16) =
                *(const uint4*)(w2s + co * 576 + t * 64 + ck * 16);
        }
        if (tid < 64) {
            float si = g1[tid] * rsqrtf(v1[tid] + 1e-4f);
            ssc[tid] = si;
            sof[tid] = 3.f * (be1[tid] - m1[tid] * si);
        }
    }
    __syncthreads();

    int w = tid >> 6, l = tid & 63;
    int lr = l & 15, lg = l >> 4;
    int abase[4], mts[4];
#pragma unroll
    for (int j = 0; j < 4; ++j) {
        int mt = w + 4 * j;
        mts[j] = mt;
        int s = mt * 4 + (lr >> 2);
        if (s > 48) s = 48;
        int qy = s / 7, qx = s - qy * 7;
        int ty = 2 * qy + ((lr >> 1) & 1);
        int tx = 2 * qx + (lr & 1);
        abase[j] = lg * 4096 + (ty * 16 + tx) * 16;
    }
    v4i acc[4][4] = {};
#pragma unroll
    for (int t = 0; t < 9; ++t) {
        int ky = t / 3, kx = t - ky * 3;
        int boff = t * 4096 + lg * 1024 + lr * 16;
        v4i bf[4];
#pragma unroll
        for (int nt = 0; nt < 4; ++nt)
            bf[nt] = *(const v4i*)(sw + boff + nt * 256);
        int aoff = (ky * 16 + kx) * 16;
#pragma unroll
        for (int j = 0; j < 4; ++j) {
            if (mts[j] < 13) {
                v4i af = *(const v4i*)(sa + abase[j] + aoff);
#pragma unroll
                for (int nt = 0; nt < 4; ++nt)
                    acc[j][nt] = __builtin_amdgcn_mfma_i32_16x16x64_i8(
                        af, bf[nt], acc[j][nt], 0, 0, 0);
            }
        }
    }

#pragma unroll
    for (int j = 0; j < 4; ++j) {
        int q = mts[j] * 4 + lg;
        if (q < 49) {
            unsigned char* outp = a2 + (size_t)b * 3136 + q * 64;
#pragma unroll
            for (int nt = 0; nt < 4; ++nt) {
                int ch = nt * 16 + lr;
                int mx = imax(imax(acc[j][nt][0], acc[j][nt][1]),
                              imax(acc[j][nt][2], acc[j][nt][3]));
                int mn = imin(imin(acc[j][nt][0], acc[j][nt][1]),
                              imin(acc[j][nt][2], acc[j][nt][3]));
                float sc = ssc[ch];
                int v = (sc >= 0.f) ? mx : mn;
                outp[ch] = (unsigned char)quant3(fmaf((float)v, sc, sof[ch]));
            }
        }
    }
}

// ---------------------------------------------------------------------------
// conv3 via i8 MFMA: 4 images per block (unchanged)
// ---------------------------------------------------------------------------
__global__ __launch_bounds__(256) void k_conv3_mfma(
    const unsigned char* __restrict__ a2, const char* __restrict__ w3s,
    const float* __restrict__ g2, const float* __restrict__ be2,
    const float* __restrict__ m2, const float* __restrict__ v2,
    unsigned char* __restrict__ a3) {
    __shared__ unsigned char sa[4 * 3136];
    __shared__ char sw[36864];
    __shared__ unsigned char so[4 * 2560];
    __shared__ float ssc[64], sof[64];
    int b0 = blockIdx.x * 4, tid = threadIdx.x;
    {
        const uint4* src = (const uint4*)(a2 + (size_t)b0 * 3136);
        for (int i = tid; i < 784; i += 256) {
            int img = i / 196, r = i - img * 196;
            int pixel = r >> 2, ck = r & 3;
            *(uint4*)(sa + img * 3136 + ck * 784 + pixel * 16) = src[i];
        }
        for (int u = tid; u < 2304; u += 256) {
            int co = u / 36, rem = u - co * 36;
            int t = rem >> 2, ck = rem & 3;
            *(uint4*)(sw + t * 4096 + ck * 1024 + co * 16) =
                *(const uint4*)(w3s + co * 576 + t * 64 + ck * 16);
        }
        if (tid < 64) {
            float si = g2[tid] * rsqrtf(v2[tid] + 1e-4f);
            ssc[tid] = si;
            sof[tid] = 3.f * (be2[tid] - m2[tid] * si);
        }
    }
    __syncthreads();

    int w = tid >> 6, l = tid & 63;
    int lr = l & 15, lg = l >> 4;
    const unsigned char* sai = sa + w * 3136;
    int abase[2];
#pragma unroll
    for (int mt = 0; mt < 2; ++mt) {
        int p = mt * 16 + lr;
        if (p > 24) p = 24;
        int oy = p / 5, ox = p - oy * 5;
        abase[mt] = lg * 784 + (oy * 7 + ox) * 16;
    }
    v4i acc[2][4] = {};
#pragma unroll
    for (int t = 0; t < 9; ++t) {
        int ky = t / 3, kx = t - ky * 3;
        int boff = t * 4096 + lg * 1024 + lr * 16;
        v4i bf[4];
#pragma unroll
        for (int nt = 0; nt < 4; ++nt)
            bf[nt] = *(const v4i*)(sw + boff + nt * 256);
        int aoff = (ky * 7 + kx) * 16;
#pragma unroll
        for (int mt = 0; mt < 2; ++mt) {
            v4i af = *(const v4i*)(sai + abase[mt] + aoff);
#pragma unroll
            for (int nt = 0; nt < 4; ++nt)
                acc[mt][nt] = __builtin_amdgcn_mfma_i32_16x16x64_i8(
                    af, bf[nt], acc[mt][nt], 0, 0, 0);
        }
    }

    unsigned char* soi = so + w * 2560;
#pragma unroll
    for (int mt = 0; mt < 2; ++mt)
#pragma unroll
        for (int nt = 0; nt < 4; ++nt) {
            int ch = nt * 16 + lr;
            float sc = ssc[ch], of = sof[ch];
#pragma unroll
            for (int r = 0; r < 4; ++r) {
                int pixel = mt * 16 + lg * 4 + r;
                soi[pixel * 80 + ch] =
                    (unsigned char)quant3(fmaf((float)acc[mt][nt][r], sc, of));
            }
        }
    __syncthreads();
    for (int idx = tid; idx < 400; idx += 256) {
        int img = idx / 100, r = idx - img * 100;
        int p = r >> 2, c0 = r & 3;
        *(uint4*)(a3 + (size_t)(b0 + img) * 1600 + r * 16) =
            *(const uint4*)(so + img * 2560 + p * 80 + c0 * 16);
    }
}

// ---------------------------------------------------------------------------
// fc1 via i8 MFMA (unchanged)
// ---------------------------------------------------------------------------
__global__ __launch_bounds__(256) void k_fc1_mfma(
    const unsigned char* __restrict__ a3, const char* __restrict__ fw1s,
    const float* __restrict__ fb1, float* __restrict__ h1) {
    __shared__ unsigned char sA[64 * 80];
    __shared__ unsigned char sB[64 * 80];
    __shared__ float sbias[64];
    int bb = (blockIdx.x >> 3) * 64;
    int ob = (blockIdx.x & 7) * 64;
    int tid = threadIdx.x;
    int row = tid >> 2, seg = tid & 3;
    if (tid < 64) sbias[tid] = fb1[ob + tid];
    const unsigned char* Ag = a3 + (size_t)(bb + row) * 1600 + seg * 16;
    const char* Bg = fw1s + (size_t)(ob + row) * 1600 + seg * 16;
    uint4 av = *(const uint4*)Ag;
    uint4 bv = *(const uint4*)Bg;

    int w = tid >> 6, l = tid & 63;
    int wm = w >> 1, wn = w & 1;
    int lr = l & 15, lg = l >> 4;
    const unsigned char* sAr = sA + (wm * 32 + lr) * 80 + lg * 16;
    const unsigned char* sBr = sB + (wn * 32 + lr) * 80 + lg * 16;
    v4i acc[2][2] = {};

    for (int k0 = 0; k0 < 1600; k0 += 64) {
        *(uint4*)(sA + row * 80 + seg * 16) = av;
        *(uint4*)(sB + row * 80 + seg * 16) = bv;
        __syncthreads();
        if (k0 < 1536) {
            av = *(const uint4*)(Ag + k0 + 64);
            bv = *(const uint4*)(Bg + k0 + 64);
        }
        v4i af0 = *(const v4i*)(sAr);
        v4i af1 = *(const v4i*)(sAr + 16 * 80);
        v4i bf0 = *(const v4i*)(sBr);
        v4i bf1 = *(const v4i*)(sBr + 16 * 80);
        acc[0][0] = __builtin_amdgcn_mfma_i32_16x16x64_i8(af0, bf0, acc[0][0], 0, 0, 0);
        acc[0][1] = __builtin_amdgcn_mfma_i32_16x16x64_i8(af0, bf1, acc[0][1], 0, 0, 0);
        acc[1][0] = __builtin_amdgcn_mfma_i32_16x16x64_i8(af1, bf0, acc[1][0], 0, 0, 0);
        acc[1][1] = __builtin_amdgcn_mfma_i32_16x16x64_i8(af1, bf1, acc[1][1], 0, 0, 0);
        __syncthreads();
    }

    const float inv3 = 1.f / 3.f;
#pragma unroll
    for (int mt = 0; mt < 2; ++mt)
#pragma unroll
        for (int nt = 0; nt < 2; ++nt) {
            int gcol = ob + wn * 32 + nt * 16 + lr;
            float bias = sbias[wn * 32 + nt * 16 + lr];
#pragma unroll
            for (int r = 0; r < 4; ++r) {
                int grow = bb + wm * 32 + mt * 16 + lg * 4 + r;
                h1[(size_t)grow * 512 + gcol] = (float)acc[mt][nt][r] * inv3 + bias;
            }
        }
}

// ---------------------------------------------------------------------------
// fc2 + log_softmax (unchanged)
// ---------------------------------------------------------------------------
__global__ __launch_bounds__(256) void k_fc2(
    const float* __restrict__ h1, const float* __restrict__ fw2,
    const float* __restrict__ fb2, float* __restrict__ out) {
    __shared__ float sw[5120];
    __shared__ float sb[16];
    int tid = threadIdx.x;
    for (int i = tid; i < 5120; i += 256) sw[i] = fw2[i];
    if (tid < 10) sb[tid] = fb2[tid];
    __syncthreads();

    int wv = tid >> 6, lane = tid & 63;
    int b = blockIdx.x * 4 + wv;
    const float* hr = h1 + (size_t)b * 512;
    float p[10];
#pragma unroll
    for (int o = 0; o < 10; ++o) p[o] = 0.f;
    for (int k = lane; k < 512; k += 64) {
        float hv = hr[k];
#pragma unroll
        for (int o = 0; o < 10; ++o) p[o] += hv * sw[o * 512 + k];
    }
#pragma unroll
    for (int o = 0; o < 10; ++o) {
#pragma unroll
        for (int off = 32; off > 0; off >>= 1) p[o] += __shfl_xor(p[o], off, 64);
        p[o] += sb[o];
    }
    float mx = p[0];
#pragma unroll
    for (int o = 1; o < 10; ++o) mx = fmaxf(mx, p[o]);
    float se = 0.f;
#pragma unroll
    for (int o = 0; o < 10; ++o) se += expf(p[o] - mx);
    float lse = logf(se) + mx;
    float myv = 0.f;
#pragma unroll
    for (int o = 0; o < 10; ++o) myv = (lane == o) ? p[o] : myv;
    if (lane < 10) out[(size_t)b * 10 + lane] = myv - lse;
}

// ---------------------------------------------------------------------------
extern "C" void kernel_launch(void* const* d_in, const int* in_sizes, int n_in,
                              void* d_out, int out_size, void* d_ws, size_t ws_size,
                              hipStream_t stream) {
    const float* x   = (const float*)d_in[0];
    const float* w1  = (const float*)d_in[1];
    const float* b1  = (const float*)d_in[2];
    const float* w2  = (const float*)d_in[3];
    const float* g1  = (const float*)d_in[4];
    const float* be1 = (const float*)d_in[5];
    const float* m1  = (const float*)d_in[6];
    const float* v1  = (const float*)d_in[7];
    const float* w3  = (const float*)d_in[8];
    const float* g2  = (const float*)d_in[9];
    const float* be2 = (const float*)d_in[10];
    const float* m2  = (const float*)d_in[11];
    const float* v2  = (const float*)d_in[12];
    const float* fw1 = (const float*)d_in[13];
    const float* fb1 = (const float*)d_in[14];
    const float* fw2 = (const float*)d_in[15];
    const float* fb2 = (const float*)d_in[16];
    float* out = (float*)d_out;

    char* ws = (char*)d_ws;
    char* w2s  = ws;                                   // 36864
    char* w3s  = ws + 36864;                           // 36864
    char* fw1s = ws + 73728;                           // 819200
    unsigned char* a1 = (unsigned char*)(ws + 892928); // 4096*12544 = 51380224
    unsigned char* a2 = a1 + 51380224;                 // 4096*3136  = 12845056
    unsigned char* a3 = a2 + 12845056;                 // 4096*1600  = 6553600
    float* h1 = (float*)(void*)a1;                     // alias: a1 dead when fc1 runs

    k_signs<<<3200, 256, 0, stream>>>(w2, w3, fw1, w2s, w3s, fw1s);
    k_conv1_mfma<<<4096, 256, 0, stream>>>(x, w1, b1, a1);
    k_conv2_mfma<<<4096, 256, 0, stream>>>(a1, w2s, g1, be1, m1, v1, a2);
    k_conv3_mfma<<<1024, 256, 0, stream>>>(a2, w3s, g2, be2, m2, v2, a3);
    k_fc1_mfma<<<512, 256, 0, stream>>>(a3, fw1s, fb1, h1);
    k_fc2<<<1024, 256, 0, stream>>>(h1, fw2, fb2, out);
}

// Round 8
// 129.276 us; speedup vs baseline: 1.2159x; 1.0779x over previous
//
#include <hip/hip_runtime.h>

#define DEV __device__ __forceinline__

typedef int v4i __attribute__((ext_vector_type(4)));
typedef short v8s __attribute__((ext_vector_type(8)));
typedef float v4f __attribute__((ext_vector_type(4)));

// quantize pre-scaled y3 = 3*y: clamp to [0,3], round-to-even
DEV unsigned int quant3(float y3) {
    return (unsigned int)(int)rintf(fminf(fmaxf(y3, 0.f), 3.f));
}

DEV int imax(int a, int b) { return a > b ? a : b; }
DEV int imin(int a, int b) { return a < b ? a : b; }

// float -> bf16 bits, round-to-nearest-even (x never NaN here)
DEV unsigned int f2bf(float x) {
    union { float f; unsigned u; } v; v.f = x;
    unsigned r = v.u + 0x7fffu + ((v.u >> 16) & 1u);
    return r >> 16;
}
DEV float bf2f(unsigned int b) {
    union { unsigned u; float f; } v; v.u = b << 16;
    return v.f;
}
#define SPLIT3(v, H, M, L)                        \
    unsigned int H = f2bf(v);                     \
    float r1_##H = (v) - bf2f(H);                 \
    unsigned int M = f2bf(r1_##H);                \
    unsigned int L = f2bf(r1_##H - bf2f(M));
#define SPLIT2(v, H, M)                           \
    unsigned int H = f2bf(v);                     \
    unsigned int M = f2bf((v) - bf2f(H));
#define SPLIT1(v, H) unsigned int H = f2bf(v);

// ---------------------------------------------------------------------------
// Sign precompute. w2/w3 [co][ci][3][3] -> w2p/w3p in the conv LDS layout
// [t][ck][co][16] (t=ky*3+kx, ck=ci>>4, cl=ci&15) so conv staging is a
// LINEAR copy (conflict-free). fw1 -> s8 [o][k] (unchanged layout).
// ---------------------------------------------------------------------------
__global__ __launch_bounds__(256) void k_signs(
    const float* __restrict__ w2, const float* __restrict__ w3,
    const float* __restrict__ fw1,
    char* __restrict__ w2p, char* __restrict__ w3p, char* __restrict__ fw1s) {
    int i = blockIdx.x * 256 + threadIdx.x;
    if (i < 36864) {
        int co = i / 576, r = i - co * 576;
        int ci = r / 9, t = r - ci * 9;
        int ck = ci >> 4, cl = ci & 15;
        int off = t * 4096 + ck * 1024 + co * 16 + cl;
        w2p[off] = (w2[i] >= 0.f) ? 1 : -1;
        w3p[off] = (w3[i] >= 0.f) ? 1 : -1;
    }
    if (i < 819200) fw1s[i] = (fw1[i] >= 0.f) ? 1 : -1;
}

// ---------------------------------------------------------------------------
// conv1 via bf16 MFMA (round-7 version, unchanged)
// ---------------------------------------------------------------------------
__global__ __launch_bounds__(256, 4) void k_conv1_mfma(
    const float* __restrict__ x, const float* __restrict__ w1f,
    const float* __restrict__ b1, unsigned char* __restrict__ a1) {
    __shared__ float sxp[30][32];
    __shared__ unsigned char sA[13312];  // 13 tiles * 1024
    __shared__ unsigned char sB[4096];   // 4 nt * 64 lanes * 16
    int b = blockIdx.x, tid = threadIdx.x;

    if (tid < 116) {
        int py, px;
        if (tid < 30)      { py = 0;  px = tid; }
        else if (tid < 60) { py = 29; px = tid - 30; }
        else if (tid < 88) { py = tid - 59; px = 0; }
        else               { py = tid - 87; px = 29; }
        sxp[py][px] = 0.f;
    }
    for (int i = tid; i < 784; i += 256) {
        int iy = i / 28, ix = i - iy * 28;
        sxp[iy + 1][ix + 1] = x[(size_t)b * 784 + i];
    }
    {
        int nt = tid >> 6, bl = tid & 63, blr = bl & 15, blg = bl >> 4;
        const float* wr = w1f + (nt * 16 + blr) * 9;
        unsigned int d[4];
#pragma unroll
        for (int jj = 0; jj < 4; ++jj) {
            int k0 = blg * 8 + jj * 2, k1 = k0 + 1;
            int t0 = (k0 * 21846) >> 16; if (t0 > 8) t0 = 8;
            int t1 = (k1 * 21846) >> 16; if (t1 > 8) t1 = 8;
            unsigned int lo16 = (k0 < 27) ? ((wr[t0] >= 0.f) ? 0x3F80u : 0xBF80u) : 0u;
            unsigned int hi16 = (k1 < 27) ? ((wr[t1] >= 0.f) ? 0x3F80u : 0xBF80u) : 0u;
            d[jj] = lo16 | (hi16 << 16);
        }
        *(uint4*)(sB + tid * 16) = make_uint4(d[0], d[1], d[2], d[3]);
    }
    int l = tid & 63, lr = l & 15, lg = l >> 4, w = tid >> 6;
    float b3[4];
#pragma unroll
    for (int nt = 0; nt < 4; ++nt) b3[nt] = 3.f * b1[nt * 16 + lr];
    __syncthreads();

    v8s bf[4];
#pragma unroll
    for (int nt = 0; nt < 4; ++nt) bf[nt] = *(const v8s*)(sB + nt * 1024 + l * 16);

    unsigned char* outb = a1 + (size_t)b * 12544;

    for (int p = 0; p < 4; ++p) {
#pragma unroll
        for (int it = 0; it < 4; ++it) {
            int s = tid + it * 256;
            if (s < 832) {
                int s4 = s >> 4;
                int blg = (s4 * 5042) >> 16;     // /13
                int mtl = s4 - blg * 13;
                int blr = s & 15;
                int mt = p * 13 + mtl;
                int q = mt * 4 + (blr >> 2); if (q > 195) q = 195;
                int qy = (q * 4682) >> 16;       // /14
                int qx = q - qy * 14;
                int cy = 2 * qy + ((blr >> 1) & 1);
                int cx = 2 * qx + (blr & 1);
                const float* p0 = &sxp[cy][cx];
                unsigned int d0, d1, d2, d3;
                if (blg == 0) {
                    float v0 = p0[0], v1 = p0[1], v2 = p0[2];
                    SPLIT3(v0, h0, m0, l0);
                    SPLIT3(v1, h1, m1, l1);
                    SPLIT2(v2, h2, m2);
                    d0 = h0 | (m0 << 16); d1 = l0 | (h1 << 16);
                    d2 = m1 | (l1 << 16); d3 = h2 | (m2 << 16);
                } else if (blg == 1) {
                    float v2 = p0[2], v3 = p0[32], v4 = p0[33], v5 = p0[34];
                    SPLIT3(v2, h2, m2, l2);
                    SPLIT3(v3, h3, m3, l3);
                    SPLIT3(v4, h4, m4, l4);
                    SPLIT1(v5, h5);
                    (void)h2; (void)m2;
                    d0 = l2 | (h3 << 16); d1 = m3 | (l3 << 16);
                    d2 = h4 | (m4 << 16); d3 = l4 | (h5 << 16);
                } else if (blg == 2) {
                    float v5 = p0[34], v6 = p0[64], v7 = p0[65];
                    SPLIT3(v5, h5, m5, l5);
                    SPLIT3(v6, h6, m6, l6);
                    SPLIT3(v7, h7, m7, l7);
                    (void)h5;
                    d0 = m5 | (l5 << 16); d1 = h6 | (m6 << 16);
                    d2 = l6 | (h7 << 16); d3 = m7 | (l7 << 16);
                } else {
                    float v8 = p0[66];
                    SPLIT3(v8, h8, m8, l8);
                    d0 = h8 | (m8 << 16); d1 = l8; d2 = 0; d3 = 0;
                }
                *(uint4*)(sA + mtl * 1024 + (blg * 16 + blr) * 16) =
                    make_uint4(d0, d1, d2, d3);
            }
        }
        __syncthreads();
        for (int mtl = w; mtl < 13; mtl += 4) {
            v8s af = *(const v8s*)(sA + mtl * 1024 + l * 16);
            int q = (p * 13 + mtl) * 4 + lg;
#pragma unroll
            for (int nt = 0; nt < 4; ++nt) {
                v4f acc = {0.f, 0.f, 0.f, 0.f};
                acc = __builtin_amdgcn_mfma_f32_16x16x32_bf16(af, bf[nt], acc, 0, 0, 0);
                if (q < 196) {
                    float mx = fmaxf(fmaxf(acc[0], acc[1]), fmaxf(acc[2], acc[3]));
                    outb[q * 64 + nt * 16 + lr] =
                        (unsigned char)quant3(fmaf(mx, 3.f, b3[nt]));
                }
            }
        }
        __syncthreads();
    }
}

// ---------------------------------------------------------------------------
// conv2 via i8 MFMA, quad-mapped M-rows. v2: LINEAR weight copy (w2p is
// pre-permuted), pixel-major act staging (conflict-free LDS writes), bn
// affine computed in epilogue from global (no ssc/sof LDS) -> 53248 B LDS
// = 3 blocks/CU.
// ---------------------------------------------------------------------------
__global__ __launch_bounds__(256, 3) void k_conv2_mfma(
    const unsigned char* __restrict__ a1, const char* __restrict__ w2p,
    const float* __restrict__ g1, const float* __restrict__ be1,
    const float* __restrict__ m1, const float* __restrict__ v1,
    unsigned char* __restrict__ a2) {
    __shared__ unsigned char sa[16384];      // [ck][16x16 padded pix][16]
    __shared__ char sw[36864];               // [t][ck][64 co][16]
    int b = blockIdx.x, tid = threadIdx.x;
    // border zeros
    if (tid < 240) {
        int ck = tid & 3, e = tid >> 2;
        int py, px;
        if (e < 16)      { py = 0;      px = e; }
        else if (e < 32) { py = 15;     px = e - 16; }
        else if (e < 46) { py = e - 31; px = 0; }
        else             { py = e - 45; px = 15; }
        *(uint4*)(sa + ck * 4096 + (py * 16 + px) * 16) = make_uint4(0, 0, 0, 0);
    }
    {
        // act: pixel-major (ck outer) -> LDS writes advance 16B/lane
        const uint4* src = (const uint4*)(a1 + (size_t)b * 12544);
        for (int i = tid; i < 784; i += 256) {
            int ck = i / 196, pixel = i - ck * 196;
            int py = pixel / 14, px = pixel - py * 14;
            *(uint4*)(sa + ck * 4096 + ((py + 1) * 16 + px + 1) * 16) =
                src[pixel * 4 + ck];
        }
        // weights: straight linear copy (w2p already in LDS layout)
        const uint4* wsrc = (const uint4*)w2p;
        uint4* wdst = (uint4*)sw;
        for (int i = tid; i < 2304; i += 256) wdst[i] = wsrc[i];
    }
    __syncthreads();

    int w = tid >> 6, l = tid & 63;
    int lr = l & 15, lg = l >> 4;
    int abase[4], mts[4];
#pragma unroll
    for (int j = 0; j < 4; ++j) {
        int mt = w + 4 * j;
        mts[j] = mt;
        int s = mt * 4 + (lr >> 2);
        if (s > 48) s = 48;
        int qy = s / 7, qx = s - qy * 7;
        int ty = 2 * qy + ((lr >> 1) & 1);
        int tx = 2 * qx + (lr & 1);
        abase[j] = lg * 4096 + (ty * 16 + tx) * 16;
    }
    v4i acc[4][4] = {};
#pragma unroll
    for (int t = 0; t < 9; ++t) {
        int ky = t / 3, kx = t - ky * 3;
        int boff = t * 4096 + lg * 1024 + lr * 16;
        v4i bf[4];
#pragma unroll
        for (int nt = 0; nt < 4; ++nt)
            bf[nt] = *(const v4i*)(sw + boff + nt * 256);
        int aoff = (ky * 16 + kx) * 16;
#pragma unroll
        for (int j = 0; j < 4; ++j) {
            if (mts[j] < 13) {
                v4i af = *(const v4i*)(sa + abase[j] + aoff);
#pragma unroll
                for (int nt = 0; nt < 4; ++nt)
                    acc[j][nt] = __builtin_amdgcn_mfma_i32_16x16x64_i8(
                        af, bf[nt], acc[j][nt], 0, 0, 0);
            }
        }
    }

    // epilogue: bn affine from global (L2-hot), in-register pool
    float sc4[4], of4[4];
#pragma unroll
    for (int nt = 0; nt < 4; ++nt) {
        int ch = nt * 16 + lr;
        float si = g1[ch] * rsqrtf(v1[ch] + 1e-4f);
        sc4[nt] = si;
        of4[nt] = 3.f * (be1[ch] - m1[ch] * si);
    }
#pragma unroll
    for (int j = 0; j < 4; ++j) {
        int q = mts[j] * 4 + lg;
        if (q < 49) {
            unsigned char* outp = a2 + (size_t)b * 3136 + q * 64;
#pragma unroll
            for (int nt = 0; nt < 4; ++nt) {
                int mx = imax(imax(acc[j][nt][0], acc[j][nt][1]),
                              imax(acc[j][nt][2], acc[j][nt][3]));
                int mn = imin(imin(acc[j][nt][0], acc[j][nt][1]),
                              imin(acc[j][nt][2], acc[j][nt][3]));
                float sc = sc4[nt];
                int v = (sc >= 0.f) ? mx : mn;
                outp[nt * 16 + lr] = (unsigned char)quant3(fmaf((float)v, sc, of4[nt]));
            }
        }
    }
}

// ---------------------------------------------------------------------------
// conv3 via i8 MFMA: 4 images/block. v2: linear weight copy, pixel-major act
// staging, bn affine from global in epilogue.
// ---------------------------------------------------------------------------
__global__ __launch_bounds__(256, 2) void k_conv3_mfma(
    const unsigned char* __restrict__ a2, const char* __restrict__ w3p,
    const float* __restrict__ g2, const float* __restrict__ be2,
    const float* __restrict__ m2, const float* __restrict__ v2,
    unsigned char* __restrict__ a3) {
    __shared__ unsigned char sa[4 * 3136];   // [img][ck][49][16]
    __shared__ char sw[36864];               // [t][ck][64 co][16]
    __shared__ unsigned char so[4 * 2560];   // [img][32 pix][80]
    int b0 = blockIdx.x * 4, tid = threadIdx.x;
    {
        // act: pixel fastest within (img, ck)
        const uint4* src = (const uint4*)(a2 + (size_t)b0 * 3136);
        for (int i = tid; i < 784; i += 256) {
            int img = i / 196, r = i - img * 196;
            int ck = r / 49, pixel = r - ck * 49;
            *(uint4*)(sa + img * 3136 + ck * 784 + pixel * 16) =
                src[img * 196 + pixel * 4 + ck];
        }
        const uint4* wsrc = (const uint4*)w3p;
        uint4* wdst = (uint4*)sw;
        for (int i = tid; i < 2304; i += 256) wdst[i] = wsrc[i];
    }
    __syncthreads();

    int w = tid >> 6, l = tid & 63;
    int lr = l & 15, lg = l >> 4;
    const unsigned char* sai = sa + w * 3136;
    int abase[2];
#pragma unroll
    for (int mt = 0; mt < 2; ++mt) {
        int p = mt * 16 + lr;
        if (p > 24) p = 24;
        int oy = p / 5, ox = p - oy * 5;
        abase[mt] = lg * 784 + (oy * 7 + ox) * 16;
    }
    v4i acc[2][4] = {};
#pragma unroll
    for (int t = 0; t < 9; ++t) {
        int ky = t / 3, kx = t - ky * 3;
        int boff = t * 4096 + lg * 1024 + lr * 16;
        v4i bf[4];
#pragma unroll
        for (int nt = 0; nt < 4; ++nt)
            bf[nt] = *(const v4i*)(sw + boff + nt * 256);
        int aoff = (ky * 7 + kx) * 16;
#pragma unroll
        for (int mt = 0; mt < 2; ++mt) {
            v4i af = *(const v4i*)(sai + abase[mt] + aoff);
#pragma unroll
            for (int nt = 0; nt < 4; ++nt)
                acc[mt][nt] = __builtin_amdgcn_mfma_i32_16x16x64_i8(
                    af, bf[nt], acc[mt][nt], 0, 0, 0);
        }
    }

    float sc4[4], of4[4];
#pragma unroll
    for (int nt = 0; nt < 4; ++nt) {
        int ch = nt * 16 + lr;
        float si = g2[ch] * rsqrtf(v2[ch] + 1e-4f);
        sc4[nt] = si;
        of4[nt] = 3.f * (be2[ch] - m2[ch] * si);
    }
    unsigned char* soi = so + w * 2560;
#pragma unroll
    for (int mt = 0; mt < 2; ++mt)
#pragma unroll
        for (int nt = 0; nt < 4; ++nt) {
            int ch = nt * 16 + lr;
#pragma unroll
            for (int r = 0; r < 4; ++r) {
                int pixel = mt * 16 + lg * 4 + r;
                soi[pixel * 80 + ch] =
                    (unsigned char)quant3(fmaf((float)acc[mt][nt][r], sc4[nt], of4[nt]));
            }
        }
    __syncthreads();
    for (int idx = tid; idx < 400; idx += 256) {
        int img = idx / 100, r = idx - img * 100;
        int p = r >> 2, c0 = r & 3;
        *(uint4*)(a3 + (size_t)(b0 + img) * 1600 + r * 16) =
            *(const uint4*)(so + img * 2560 + p * 80 + c0 * 16);
    }
}

// ---------------------------------------------------------------------------
// fc1 via i8 MFMA (unchanged)
// ---------------------------------------------------------------------------
__global__ __launch_bounds__(256) void k_fc1_mfma(
    const unsigned char* __restrict__ a3, const char* __restrict__ fw1s,
    const float* __restrict__ fb1, float* __restrict__ h1) {
    __shared__ unsigned char sA[64 * 80];
    __shared__ unsigned char sB[64 * 80];
    __shared__ float sbias[64];
    int bb = (blockIdx.x >> 3) * 64;
    int ob = (blockIdx.x & 7) * 64;
    int tid = threadIdx.x;
    int row = tid >> 2, seg = tid & 3;
    if (tid < 64) sbias[tid] = fb1[ob + tid];
    const unsigned char* Ag = a3 + (size_t)(bb + row) * 1600 + seg * 16;
    const char* Bg = fw1s + (size_t)(ob + row) * 1600 + seg * 16;
    uint4 av = *(const uint4*)Ag;
    uint4 bv = *(const uint4*)Bg;

    int w = tid >> 6, l = tid & 63;
    int wm = w >> 1, wn = w & 1;
    int lr = l & 15, lg = l >> 4;
    const unsigned char* sAr = sA + (wm * 32 + lr) * 80 + lg * 16;
    const unsigned char* sBr = sB + (wn * 32 + lr) * 80 + lg * 16;
    v4i acc[2][2] = {};

    for (int k0 = 0; k0 < 1600; k0 += 64) {
        *(uint4*)(sA + row * 80 + seg * 16) = av;
        *(uint4*)(sB + row * 80 + seg * 16) = bv;
        __syncthreads();
        if (k0 < 1536) {
            av = *(const uint4*)(Ag + k0 + 64);
            bv = *(const uint4*)(Bg + k0 + 64);
        }
        v4i af0 = *(const v4i*)(sAr);
        v4i af1 = *(const v4i*)(sAr + 16 * 80);
        v4i bf0 = *(const v4i*)(sBr);
        v4i bf1 = *(const v4i*)(sBr + 16 * 80);
        acc[0][0] = __builtin_amdgcn_mfma_i32_16x16x64_i8(af0, bf0, acc[0][0], 0, 0, 0);
        acc[0][1] = __builtin_amdgcn_mfma_i32_16x16x64_i8(af0, bf1, acc[0][1], 0, 0, 0);
        acc[1][0] = __builtin_amdgcn_mfma_i32_16x16x64_i8(af1, bf0, acc[1][0], 0, 0, 0);
        acc[1][1] = __builtin_amdgcn_mfma_i32_16x16x64_i8(af1, bf1, acc[1][1], 0, 0, 0);
        __syncthreads();
    }

    const float inv3 = 1.f / 3.f;
#pragma unroll
    for (int mt = 0; mt < 2; ++mt)
#pragma unroll
        for (int nt = 0; nt < 2; ++nt) {
            int gcol = ob + wn * 32 + nt * 16 + lr;
            float bias = sbias[wn * 32 + nt * 16 + lr];
#pragma unroll
            for (int r = 0; r < 4; ++r) {
                int grow = bb + wm * 32 + mt * 16 + lg * 4 + r;
                h1[(size_t)grow * 512 + gcol] = (float)acc[mt][nt][r] * inv3 + bias;
            }
        }
}

// ---------------------------------------------------------------------------
// fc2 + log_softmax (unchanged)
// ---------------------------------------------------------------------------
__global__ __launch_bounds__(256) void k_fc2(
    const float* __restrict__ h1, const float* __restrict__ fw2,
    const float* __restrict__ fb2, float* __restrict__ out) {
    __shared__ float sw[5120];
    __shared__ float sb[16];
    int tid = threadIdx.x;
    for (int i = tid; i < 5120; i += 256) sw[i] = fw2[i];
    if (tid < 10) sb[tid] = fb2[tid];
    __syncthreads();

    int wv = tid >> 6, lane = tid & 63;
    int b = blockIdx.x * 4 + wv;
    const float* hr = h1 + (size_t)b * 512;
    float p[10];
#pragma unroll
    for (int o = 0; o < 10; ++o) p[o] = 0.f;
    for (int k = lane; k < 512; k += 64) {
        float hv = hr[k];
#pragma unroll
        for (int o = 0; o < 10; ++o) p[o] += hv * sw[o * 512 + k];
    }
#pragma unroll
    for (int o = 0; o < 10; ++o) {
#pragma unroll
        for (int off = 32; off > 0; off >>= 1) p[o] += __shfl_xor(p[o], off, 64);
        p[o] += sb[o];
    }
    float mx = p[0];
#pragma unroll
    for (int o = 1; o < 10; ++o) mx = fmaxf(mx, p[o]);
    float se = 0.f;
#pragma unroll
    for (int o = 0; o < 10; ++o) se += expf(p[o] - mx);
    float lse = logf(se) + mx;
    float myv = 0.f;
#pragma unroll
    for (int o = 0; o < 10; ++o) myv = (lane == o) ? p[o] : myv;
    if (lane < 10) out[(size_t)b * 10 + lane] = myv - lse;
}

// ---------------------------------------------------------------------------
extern "C" void kernel_launch(void* const* d_in, const int* in_sizes, int n_in,
                              void* d_out, int out_size, void* d_ws, size_t ws_size,
                              hipStream_t stream) {
    const float* x   = (const float*)d_in[0];
    const float* w1  = (const float*)d_in[1];
    const float* b1  = (const float*)d_in[2];
    const float* w2  = (const float*)d_in[3];
    const float* g1  = (const float*)d_in[4];
    const float* be1 = (const float*)d_in[5];
    const float* m1  = (const float*)d_in[6];
    const float* v1  = (const float*)d_in[7];
    const float* w3  = (const float*)d_in[8];
    const float* g2  = (const float*)d_in[9];
    const float* be2 = (const float*)d_in[10];
    const float* m2  = (const float*)d_in[11];
    const float* v2  = (const float*)d_in[12];
    const float* fw1 = (const float*)d_in[13];
    const float* fb1 = (const float*)d_in[14];
    const float* fw2 = (const float*)d_in[15];
    const float* fb2 = (const float*)d_in[16];
    float* out = (float*)d_out;

    char* ws = (char*)d_ws;
    char* w2p  = ws;                                   // 36864
    char* w3p  = ws + 36864;                           // 36864
    char* fw1s = ws + 73728;                           // 819200
    unsigned char* a1 = (unsigned char*)(ws + 892928); // 4096*12544 = 51380224
    unsigned char* a2 = a1 + 51380224;                 // 4096*3136  = 12845056
    unsigned char* a3 = a2 + 12845056;                 // 4096*1600  = 6553600
    float* h1 = (float*)(void*)a1;                     // alias: a1 dead when fc1 runs

    k_signs<<<3200, 256, 0, stream>>>(w2, w3, fw1, w2p, w3p, fw1s);
    k_conv1_mfma<<<4096, 256, 0, stream>>>(x, w1, b1, a1);
    k_conv2_mfma<<<4096, 256, 0, stream>>>(a1, w2p, g1, be1, m1, v1, a2);
    k_conv3_mfma<<<1024, 256, 0, stream>>>(a2, w3p, g2, be2, m2, v2, a3);
    k_fc1_mfma<<<512, 256, 0, stream>>>(a3, fw1s, fb1, h1);
    k_fc2<<<1024, 256, 0, stream>>>(h1, fw2, fb2, out);
}

// Round 9
// 127.398 us; speedup vs baseline: 1.2338x; 1.0147x over previous
//
#include <hip/hip_runtime.h>

#define DEV __device__ __forceinline__

typedef int v4i __attribute__((ext_vector_type(4)));
typedef short v8s __attribute__((ext_vector_type(8)));
typedef float v4f __attribute__((ext_vector_type(4)));
typedef unsigned long long u64;

// quantize pre-scaled y3 = 3*y: clamp to [0,3], round-to-even
DEV unsigned int quant3(float y3) {
    return (unsigned int)(int)rintf(fminf(fmaxf(y3, 0.f), 3.f));
}

DEV int imax(int a, int b) { return a > b ? a : b; }
DEV int imin(int a, int b) { return a < b ? a : b; }

// float -> bf16 bits, round-to-nearest-even (x never NaN here)
DEV unsigned int f2bf(float x) {
    union { float f; unsigned u; } v; v.f = x;
    unsigned r = v.u + 0x7fffu + ((v.u >> 16) & 1u);
    return r >> 16;
}
DEV float bf2f(unsigned int b) {
    union { unsigned u; float f; } v; v.u = b << 16;
    return v.f;
}
#define SPLIT3(v, H, M, L)                        \
    unsigned int H = f2bf(v);                     \
    float r1_##H = (v) - bf2f(H);                 \
    unsigned int M = f2bf(r1_##H);                \
    unsigned int L = f2bf(r1_##H - bf2f(M));

DEV v8s mk_v8s(u64 a, u64 b) {
    union { u64 q[2]; v8s s; } u; u.q[0] = a; u.q[1] = b; return u.s;
}

// channel-permutation: channel c stored at byte pos(c) within each 64B pixel
// vector (so a lane's 4 nt-bytes pack into one dword: pos(nt*16+lr)=lr*4+nt).
DEV int chpos(int c) { return (c & 15) * 4 + (c >> 4); }

// ---------------------------------------------------------------------------
// Sign precompute. w2/w3 [co][ci][3][3] -> w2p/w3p in conv LDS layout
// [t][ck][co][16] with the ci-dimension PERMUTED by chpos (a1/a2 store
// channels permuted). fw1 -> s8 [o][pix][64] with ch permuted (a3 permuted).
// ---------------------------------------------------------------------------
__global__ __launch_bounds__(256) void k_signs(
    const float* __restrict__ w2, const float* __restrict__ w3,
    const float* __restrict__ fw1,
    char* __restrict__ w2p, char* __restrict__ w3p, char* __restrict__ fw1s) {
    int i = blockIdx.x * 256 + threadIdx.x;
    if (i < 36864) {
        int co = i / 576, r = i - co * 576;
        int ci = r / 9, t = r - ci * 9;
        int p = chpos(ci);
        int off = t * 4096 + (p >> 4) * 1024 + co * 16 + (p & 15);
        w2p[off] = (w2[i] >= 0.f) ? 1 : -1;
        w3p[off] = (w3[i] >= 0.f) ? 1 : -1;
    }
    if (i < 819200) {
        int o = i / 1600, r2 = i - o * 1600;
        int pix = r2 >> 6, ch = r2 & 63;
        fw1s[o * 1600 + pix * 64 + chpos(ch)] = (fw1[i] >= 0.f) ? 1 : -1;
    }
}

// ---------------------------------------------------------------------------
// conv1 via bf16 MFMA, v5 (no im2col):
//  - split each padded pixel ONCE -> LDS record 8B = (hi|mid, lo|0), grid
//    [30 rows][32 cols] (cols 30/31 zeroed -> no garbage reads).
//  - K layout per tap-row ky: k = kx*4 + slot(hi,mid,lo,0); A-fragment for
//    lane (lr,lg) = two b64 reads at window base + (lg&1)*16. lg>=2 B-frags
//    are ZERO, so reads are branchless/harmless.
//  - 3 chained MFMAs (ky) per (tile,nt); quad-mapped M rows -> lane's 4 acc
//    f32 = one 2x2 pool window -> 3 fmax; 49 M-tiles exactly (196 quads).
//  - output channel-permuted: lane packs 4 nt-bytes -> 1 dword store.
// LDS 7.7 KB; B-frags+acc ~70 VGPR; 4 blocks/CU.
// ---------------------------------------------------------------------------
__global__ __launch_bounds__(256, 4) void k_conv1_mfma(
    const float* __restrict__ x, const float* __restrict__ w1f,
    const float* __restrict__ b1, unsigned char* __restrict__ a1) {
    __shared__ u64 simg[960];   // [30][32] 8B records
    int b = blockIdx.x, tid = threadIdx.x;
    for (int i = tid; i < 960; i += 256) {
        int y = i >> 5, xc = i & 31;
        float v = 0.f;
        if (y >= 1 && y <= 28 && xc >= 1 && xc <= 28)
            v = x[(size_t)b * 784 + (y - 1) * 28 + (xc - 1)];
        SPLIT3(v, h, m, lo);
        simg[i] = (u64)(h | (m << 16)) | ((u64)lo << 32);
    }
    int l = tid & 63, lr = l & 15, lg = l >> 4, w = tid >> 6;
    // B fragments: sign replicated across (hi,mid,lo) slots, 0 in pad slot.
    v8s bf[3][4];
    float b3[4];
#pragma unroll
    for (int nt = 0; nt < 4; ++nt) {
        b3[nt] = 3.f * b1[nt * 16 + lr];
#pragma unroll
        for (int ky = 0; ky < 3; ++ky) {
            const float* wr = w1f + (nt * 16 + lr) * 9 + ky * 3;
            unsigned s0 = (wr[0] >= 0.f) ? 0x3F80u : 0xBF80u;
            unsigned s1 = (wr[1] >= 0.f) ? 0x3F80u : 0xBF80u;
            unsigned s2 = (wr[2] >= 0.f) ? 0x3F80u : 0xBF80u;
            unsigned d0 = 0, d1 = 0, d2 = 0, d3 = 0;
            if (lg == 0) { d0 = s0 | (s0 << 16); d1 = s0; d2 = s1 | (s1 << 16); d3 = s1; }
            if (lg == 1) { d0 = s2 | (s2 << 16); d1 = s2; }
            union { unsigned d[4]; v8s s; } u;
            u.d[0] = d0; u.d[1] = d1; u.d[2] = d2; u.d[3] = d3;
            bf[ky][nt] = u.s;
        }
    }
    __syncthreads();

    const unsigned char* sib = (const unsigned char*)simg;
    unsigned char* outb = a1 + (size_t)b * 12544;
    int off16 = (lg & 1) << 4;
    for (int mt = w; mt < 49; mt += 4) {
        int s = mt * 4 + (lr >> 2);
        int qy = s / 14, qx = s - qy * 14;
        int cy = 2 * qy + ((lr >> 1) & 1);
        int cx = 2 * qx + (lr & 1);
        int abase = (cy * 32 + cx) * 8 + off16;
        v4f a0 = {0.f, 0.f, 0.f, 0.f}, a1v = {0.f, 0.f, 0.f, 0.f};
        v4f a2v = {0.f, 0.f, 0.f, 0.f}, a3v = {0.f, 0.f, 0.f, 0.f};
#pragma unroll
        for (int ky = 0; ky < 3; ++ky) {
            u64 qa = *(const u64*)(sib + abase + ky * 256);
            u64 qb = *(const u64*)(sib + abase + ky * 256 + 8);
            v8s af = mk_v8s(qa, qb);
            a0 = __builtin_amdgcn_mfma_f32_16x16x32_bf16(af, bf[ky][0], a0, 0, 0, 0);
            a1v = __builtin_amdgcn_mfma_f32_16x16x32_bf16(af, bf[ky][1], a1v, 0, 0, 0);
            a2v = __builtin_amdgcn_mfma_f32_16x16x32_bf16(af, bf[ky][2], a2v, 0, 0, 0);
            a3v = __builtin_amdgcn_mfma_f32_16x16x32_bf16(af, bf[ky][3], a3v, 0, 0, 0);
        }
        unsigned dw;
        {
            float m0 = fmaxf(fmaxf(a0[0], a0[1]), fmaxf(a0[2], a0[3]));
            float m1 = fmaxf(fmaxf(a1v[0], a1v[1]), fmaxf(a1v[2], a1v[3]));
            float m2 = fmaxf(fmaxf(a2v[0], a2v[1]), fmaxf(a2v[2], a2v[3]));
            float m3 = fmaxf(fmaxf(a3v[0], a3v[1]), fmaxf(a3v[2], a3v[3]));
            dw  = quant3(fmaf(m0, 3.f, b3[0]));
            dw |= quant3(fmaf(m1, 3.f, b3[1])) << 8;
            dw |= quant3(fmaf(m2, 3.f, b3[2])) << 16;
            dw |= quant3(fmaf(m3, 3.f, b3[3])) << 24;
        }
        int q = mt * 4 + lg;
        *(unsigned*)(outb + q * 64 + lr * 4) = dw;
    }
}

// ---------------------------------------------------------------------------
// conv2 via i8 MFMA, quad-mapped M-rows, linear staging (R8) + packed dword
// epilogue (channel-permuted output; permutation baked into w3p).
// ---------------------------------------------------------------------------
__global__ __launch_bounds__(256, 3) void k_conv2_mfma(
    const unsigned char* __restrict__ a1, const char* __restrict__ w2p,
    const float* __restrict__ g1, const float* __restrict__ be1,
    const float* __restrict__ m1, const float* __restrict__ v1,
    unsigned char* __restrict__ a2) {
    __shared__ unsigned char sa[16384];      // [ck][16x16 padded pix][16]
    __shared__ char sw[36864];               // [t][ck][64 co][16]
    int b = blockIdx.x, tid = threadIdx.x;
    if (tid < 240) {
        int ck = tid & 3, e = tid >> 2;
        int py, px;
        if (e < 16)      { py = 0;      px = e; }
        else if (e < 32) { py = 15;     px = e - 16; }
        else if (e < 46) { py = e - 31; px = 0; }
        else             { py = e - 45; px = 15; }
        *(uint4*)(sa + ck * 4096 + (py * 16 + px) * 16) = make_uint4(0, 0, 0, 0);
    }
    {
        const uint4* src = (const uint4*)(a1 + (size_t)b * 12544);
        for (int i = tid; i < 784; i += 256) {
            int ck = i / 196, pixel = i - ck * 196;
            int py = pixel / 14, px = pixel - py * 14;
            *(uint4*)(sa + ck * 4096 + ((py + 1) * 16 + px + 1) * 16) =
                src[pixel * 4 + ck];
        }
        const uint4* wsrc = (const uint4*)w2p;
        uint4* wdst = (uint4*)sw;
        for (int i = tid; i < 2304; i += 256) wdst[i] = wsrc[i];
    }
    __syncthreads();

    int w = tid >> 6, l = tid & 63;
    int lr = l & 15, lg = l >> 4;
    int abase[4], mts[4];
#pragma unroll
    for (int j = 0; j < 4; ++j) {
        int mt = w + 4 * j;
        mts[j] = mt;
        int s = mt * 4 + (lr >> 2);
        if (s > 48) s = 48;
        int qy = s / 7, qx = s - qy * 7;
        int ty = 2 * qy + ((lr >> 1) & 1);
        int tx = 2 * qx + (lr & 1);
        abase[j] = lg * 4096 + (ty * 16 + tx) * 16;
    }
    v4i acc[4][4] = {};
#pragma unroll
    for (int t = 0; t < 9; ++t) {
        int ky = t / 3, kx = t - ky * 3;
        int boff = t * 4096 + lg * 1024 + lr * 16;
        v4i bfw[4];
#pragma unroll
        for (int nt = 0; nt < 4; ++nt)
            bfw[nt] = *(const v4i*)(sw + boff + nt * 256);
        int aoff = (ky * 16 + kx) * 16;
#pragma unroll
        for (int j = 0; j < 4; ++j) {
            if (mts[j] < 13) {
                v4i af = *(const v4i*)(sa + abase[j] + aoff);
#pragma unroll
                for (int nt = 0; nt < 4; ++nt)
                    acc[j][nt] = __builtin_amdgcn_mfma_i32_16x16x64_i8(
                        af, bfw[nt], acc[j][nt], 0, 0, 0);
            }
        }
    }

    float sc4[4], of4[4];
#pragma unroll
    for (int nt = 0; nt < 4; ++nt) {
        int ch = nt * 16 + lr;
        float si = g1[ch] * rsqrtf(v1[ch] + 1e-4f);
        sc4[nt] = si;
        of4[nt] = 3.f * (be1[ch] - m1[ch] * si);
    }
#pragma unroll
    for (int j = 0; j < 4; ++j) {
        int q = mts[j] * 4 + lg;
        if (q < 49) {
            unsigned dw = 0;
#pragma unroll
            for (int nt = 0; nt < 4; ++nt) {
                int mx = imax(imax(acc[j][nt][0], acc[j][nt][1]),
                              imax(acc[j][nt][2], acc[j][nt][3]));
                int mn = imin(imin(acc[j][nt][0], acc[j][nt][1]),
                              imin(acc[j][nt][2], acc[j][nt][3]));
                float sc = sc4[nt];
                int v = (sc >= 0.f) ? mx : mn;
                dw |= quant3(fmaf((float)v, sc, of4[nt])) << (8 * nt);
            }
            *(unsigned*)(a2 + (size_t)b * 3136 + q * 64 + lr * 4) = dw;
        }
    }
}

// ---------------------------------------------------------------------------
// conv3 via i8 MFMA: 4 images/block; packed dword epilogue (permuted output,
// baked into fw1s).
// ---------------------------------------------------------------------------
__global__ __launch_bounds__(256, 2) void k_conv3_mfma(
    const unsigned char* __restrict__ a2, const char* __restrict__ w3p,
    const float* __restrict__ g2, const float* __restrict__ be2,
    const float* __restrict__ m2, const float* __restrict__ v2,
    unsigned char* __restrict__ a3) {
    __shared__ unsigned char sa[4 * 3136];   // [img][ck][49][16]
    __shared__ char sw[36864];               // [t][ck][64 co][16]
    __shared__ unsigned char so[4 * 2560];   // [img][32 pix][80]
    int b0 = blockIdx.x * 4, tid = threadIdx.x;
    {
        const uint4* src = (const uint4*)(a2 + (size_t)b0 * 3136);
        for (int i = tid; i < 784; i += 256) {
            int img = i / 196, r = i - img * 196;
            int ck = r / 49, pixel = r - ck * 49;
            *(uint4*)(sa + img * 3136 + ck * 784 + pixel * 16) =
                src[img * 196 + pixel * 4 + ck];
        }
        const uint4* wsrc = (const uint4*)w3p;
        uint4* wdst = (uint4*)sw;
        for (int i = tid; i < 2304; i += 256) wdst[i] = wsrc[i];
    }
    __syncthreads();

    int w = tid >> 6, l = tid & 63;
    int lr = l & 15, lg = l >> 4;
    const unsigned char* sai = sa + w * 3136;
    int abase[2];
#pragma unroll
    for (int mt = 0; mt < 2; ++mt) {
        int p = mt * 16 + lr;
        if (p > 24) p = 24;
        int oy = p / 5, ox = p - oy * 5;
        abase[mt] = lg * 784 + (oy * 7 + ox) * 16;
    }
    v4i acc[2][4] = {};
#pragma unroll
    for (int t = 0; t < 9; ++t) {
        int ky = t / 3, kx = t - ky * 3;
        int boff = t * 4096 + lg * 1024 + lr * 16;
        v4i bfw[4];
#pragma unroll
        for (int nt = 0; nt < 4; ++nt)
            bfw[nt] = *(const v4i*)(sw + boff + nt * 256);
        int aoff = (ky * 7 + kx) * 16;
#pragma unroll
        for (int mt = 0; mt < 2; ++mt) {
            v4i af = *(const v4i*)(sai + abase[mt] + aoff);
#pragma unroll
            for (int nt = 0; nt < 4; ++nt)
                acc[mt][nt] = __builtin_amdgcn_mfma_i32_16x16x64_i8(
                    af, bfw[nt], acc[mt][nt], 0, 0, 0);
        }
    }

    float sc4[4], of4[4];
#pragma unroll
    for (int nt = 0; nt < 4; ++nt) {
        int ch = nt * 16 + lr;
        float si = g2[ch] * rsqrtf(v2[ch] + 1e-4f);
        sc4[nt] = si;
        of4[nt] = 3.f * (be2[ch] - m2[ch] * si);
    }
    unsigned char* soi = so + w * 2560;
#pragma unroll
    for (int mt = 0; mt < 2; ++mt)
#pragma unroll
        for (int r = 0; r < 4; ++r) {
            int pixel = mt * 16 + lg * 4 + r;
            unsigned dw = 0;
#pragma unroll
            for (int nt = 0; nt < 4; ++nt)
                dw |= quant3(fmaf((float)acc[mt][nt][r], sc4[nt], of4[nt])) << (8 * nt);
            *(unsigned*)(soi + pixel * 80 + lr * 4) = dw;
        }
    __syncthreads();
    for (int idx = tid; idx < 400; idx += 256) {
        int img = idx / 100, r = idx - img * 100;
        int p = r >> 2, c0 = r & 3;
        *(uint4*)(a3 + (size_t)(b0 + img) * 1600 + r * 16) =
            *(const uint4*)(so + img * 2560 + p * 80 + c0 * 16);
    }
}

// ---------------------------------------------------------------------------
// fc1 via i8 MFMA (unchanged; fw1s columns pre-permuted to match a3)
// ---------------------------------------------------------------------------
__global__ __launch_bounds__(256) void k_fc1_mfma(
    const unsigned char* __restrict__ a3, const char* __restrict__ fw1s,
    const float* __restrict__ fb1, float* __restrict__ h1) {
    __shared__ unsigned char sA[64 * 80];
    __shared__ unsigned char sB[64 * 80];
    __shared__ float sbias[64];
    int bb = (blockIdx.x >> 3) * 64;
    int ob = (blockIdx.x & 7) * 64;
    int tid = threadIdx.x;
    int row = tid >> 2, seg = tid & 3;
    if (tid < 64) sbias[tid] = fb1[ob + tid];
    const unsigned char* Ag = a3 + (size_t)(bb + row) * 1600 + seg * 16;
    const char* Bg = fw1s + (size_t)(ob + row) * 1600 + seg * 16;
    uint4 av = *(const uint4*)Ag;
    uint4 bv = *(const uint4*)Bg;

    int w = tid >> 6, l = tid & 63;
    int wm = w >> 1, wn = w & 1;
    int lr = l & 15, lg = l >> 4;
    const unsigned char* sAr = sA + (wm * 32 + lr) * 80 + lg * 16;
    const unsigned char* sBr = sB + (wn * 32 + lr) * 80 + lg * 16;
    v4i acc[2][2] = {};

    for (int k0 = 0; k0 < 1600; k0 += 64) {
        *(uint4*)(sA + row * 80 + seg * 16) = av;
        *(uint4*)(sB + row * 80 + seg * 16) = bv;
        __syncthreads();
        if (k0 < 1536) {
            av = *(const uint4*)(Ag + k0 + 64);
            bv = *(const uint4*)(Bg + k0 + 64);
        }
        v4i af0 = *(const v4i*)(sAr);
        v4i af1 = *(const v4i*)(sAr + 16 * 80);
        v4i bf0 = *(const v4i*)(sBr);
        v4i bf1 = *(const v4i*)(sBr + 16 * 80);
        acc[0][0] = __builtin_amdgcn_mfma_i32_16x16x64_i8(af0, bf0, acc[0][0], 0, 0, 0);
        acc[0][1] = __builtin_amdgcn_mfma_i32_16x16x64_i8(af0, bf1, acc[0][1], 0, 0, 0);
        acc[1][0] = __builtin_amdgcn_mfma_i32_16x16x64_i8(af1, bf0, acc[1][0], 0, 0, 0);
        acc[1][1] = __builtin_amdgcn_mfma_i32_16x16x64_i8(af1, bf1, acc[1][1], 0, 0, 0);
        __syncthreads();
    }

    const float inv3 = 1.f / 3.f;
#pragma unroll
    for (int mt = 0; mt < 2; ++mt)
#pragma unroll
        for (int nt = 0; nt < 2; ++nt) {
            int gcol = ob + wn * 32 + nt * 16 + lr;
            float bias = sbias[wn * 32 + nt * 16 + lr];
#pragma unroll
            for (int r = 0; r < 4; ++r) {
                int grow = bb + wm * 32 + mt * 16 + lg * 4 + r;
                h1[(size_t)grow * 512 + gcol] = (float)acc[mt][nt][r] * inv3 + bias;
            }
        }
}

// ---------------------------------------------------------------------------
// fc2 + log_softmax (unchanged)
// ---------------------------------------------------------------------------
__global__ __launch_bounds__(256) void k_fc2(
    const float* __restrict__ h1, const float* __restrict__ fw2,
    const float* __restrict__ fb2, float* __restrict__ out) {
    __shared__ float sw[5120];
    __shared__ float sb[16];
    int tid = threadIdx.x;
    for (int i = tid; i < 5120; i += 256) sw[i] = fw2[i];
    if (tid < 10) sb[tid] = fb2[tid];
    __syncthreads();

    int wv = tid >> 6, lane = tid & 63;
    int b = blockIdx.x * 4 + wv;
    const float* hr = h1 + (size_t)b * 512;
    float p[10];
#pragma unroll
    for (int o = 0; o < 10; ++o) p[o] = 0.f;
    for (int k = lane; k < 512; k += 64) {
        float hv = hr[k];
#pragma unroll
        for (int o = 0; o < 10; ++o) p[o] += hv * sw[o * 512 + k];
    }
#pragma unroll
    for (int o = 0; o < 10; ++o) {
#pragma unroll
        for (int off = 32; off > 0; off >>= 1) p[o] += __shfl_xor(p[o], off, 64);
        p[o] += sb[o];
    }
    float mx = p[0];
#pragma unroll
    for (int o = 1; o < 10; ++o) mx = fmaxf(mx, p[o]);
    float se = 0.f;
#pragma unroll
    for (int o = 0; o < 10; ++o) se += expf(p[o] - mx);
    float lse = logf(se) + mx;
    float myv = 0.f;
#pragma unroll
    for (int o = 0; o < 10; ++o) myv = (lane == o) ? p[o] : myv;
    if (lane < 10) out[(size_t)b * 10 + lane] = myv - lse;
}

// ---------------------------------------------------------------------------
extern "C" void kernel_launch(void* const* d_in, const int* in_sizes, int n_in,
                              void* d_out, int out_size, void* d_ws, size_t ws_size,
                              hipStream_t stream) {
    const float* x   = (const float*)d_in[0];
    const float* w1  = (const float*)d_in[1];
    const float* b1  = (const float*)d_in[2];
    const float* w2  = (const float*)d_in[3];
    const float* g1  = (const float*)d_in[4];
    const float* be1 = (const float*)d_in[5];
    const float* m1  = (const float*)d_in[6];
    const float* v1  = (const float*)d_in[7];
    const float* w3  = (const float*)d_in[8];
    const float* g2  = (const float*)d_in[9];
    const float* be2 = (const float*)d_in[10];
    const float* m2  = (const float*)d_in[11];
    const float* v2  = (const float*)d_in[12];
    const float* fw1 = (const float*)d_in[13];
    const float* fb1 = (const float*)d_in[14];
    const float* fw2 = (const float*)d_in[15];
    const float* fb2 = (const float*)d_in[16];
    float* out = (float*)d_out;

    char* ws = (char*)d_ws;
    char* w2p  = ws;                                   // 36864
    char* w3p  = ws + 36864;                           // 36864
    char* fw1s = ws + 73728;                           // 819200
    unsigned char* a1 = (unsigned char*)(ws + 892928); // 4096*12544 = 51380224
    unsigned char* a2 = a1 + 51380224;                 // 4096*3136  = 12845056
    unsigned char* a3 = a2 + 12845056;                 // 4096*1600  = 6553600
    float* h1 = (float*)(void*)a1;                     // alias: a1 dead when fc1 runs

    k_signs<<<3200, 256, 0, stream>>>(w2, w3, fw1, w2p, w3p, fw1s);
    k_conv1_mfma<<<4096, 256, 0, stream>>>(x, w1, b1, a1);
    k_conv2_mfma<<<4096, 256, 0, stream>>>(a1, w2p, g1, be1, m1, v1, a2);
    k_conv3_mfma<<<1024, 256, 0, stream>>>(a2, w3p, g2, be2, m2, v2, a3);
    k_fc1_mfma<<<512, 256, 0, stream>>>(a3, fw1s, fb1, h1);
    k_fc2<<<1024, 256, 0, stream>>>(h1, fw2, fb2, out);
}

// Round 10
// 113.332 us; speedup vs baseline: 1.3870x; 1.1241x over previous
//
#include <hip/hip_runtime.h>

#define DEV __device__ __forceinline__

typedef int v4i __attribute__((ext_vector_type(4)));
typedef short v8s __attribute__((ext_vector_type(8)));
typedef float v4f __attribute__((ext_vector_type(4)));
typedef unsigned long long u64;

// quantize pre-scaled y3 = 3*y: clamp to [0,3], round-to-even
DEV unsigned int quant3(float y3) {
    return (unsigned int)(int)rintf(fminf(fmaxf(y3, 0.f), 3.f));
}

DEV int imax(int a, int b) { return a > b ? a : b; }
DEV int imin(int a, int b) { return a < b ? a : b; }

// float -> bf16 bits, round-to-nearest-even (x never NaN here)
DEV unsigned int f2bf(float x) {
    union { float f; unsigned u; } v; v.f = x;
    unsigned r = v.u + 0x7fffu + ((v.u >> 16) & 1u);
    return r >> 16;
}
DEV float bf2f(unsigned int b) {
    union { unsigned u; float f; } v; v.u = b << 16;
    return v.f;
}
#define SPLIT3(v, H, M, L)                        \
    unsigned int H = f2bf(v);                     \
    float r1_##H = (v) - bf2f(H);                 \
    unsigned int M = f2bf(r1_##H);                \
    unsigned int L = f2bf(r1_##H - bf2f(M));

DEV v8s mk_v8s(u64 a, u64 b) {
    union { u64 q[2]; v8s s; } u; u.q[0] = a; u.q[1] = b; return u.s;
}

// channel-permutation: channel c stored at byte pos(c) within each 64B pixel
// vector (so a lane's 4 nt-bytes pack into one dword: pos(nt*16+lr)=lr*4+nt).
DEV int chpos(int c) { return (c & 15) * 4 + (c >> 4); }

// ---------------------------------------------------------------------------
// Sign precompute. w2/w3 [co][ci][3][3] -> w2p/w3p in conv LDS layout
// [t][ck][co][16] with the ci-dimension PERMUTED by chpos (a1/a2 store
// channels permuted). fw1 -> s8 [o][pix][64] with ch permuted (a3 permuted).
// ---------------------------------------------------------------------------
__global__ __launch_bounds__(256) void k_signs(
    const float* __restrict__ w2, const float* __restrict__ w3,
    const float* __restrict__ fw1,
    char* __restrict__ w2p, char* __restrict__ w3p, char* __restrict__ fw1s) {
    int i = blockIdx.x * 256 + threadIdx.x;
    if (i < 36864) {
        int co = i / 576, r = i - co * 576;
        int ci = r / 9, t = r - ci * 9;
        int p = chpos(ci);
        int off = t * 4096 + (p >> 4) * 1024 + co * 16 + (p & 15);
        w2p[off] = (w2[i] >= 0.f) ? 1 : -1;
        w3p[off] = (w3[i] >= 0.f) ? 1 : -1;
    }
    if (i < 819200) {
        int o = i / 1600, r2 = i - o * 1600;
        int pix = r2 >> 6, ch = r2 & 63;
        fw1s[o * 1600 + pix * 64 + chpos(ch)] = (fw1[i] >= 0.f) ? 1 : -1;
    }
}

// ---------------------------------------------------------------------------
// conv1 via bf16 MFMA, v6 (full-K):
//  - split each padded pixel ONCE -> 8B LDS record (hi|mid, lo|0), [30][32];
//    also keep the fp32 padded image in LDS.
//  - K layout: lane group lg owns taps {2lg, 2lg+1}, slots (h,m,l,0) each ->
//    32 slots EXACTLY. A-frag = two ds_read_b64 of the records at the lane's
//    window + tap offsets. ONE K=32 MFMA per (tile, nt): 196 MFMA/image.
//  - tap 8 (ky=kx=2) added EXACTLY on VALU: acc[nt][r] += sign8[nt]*x8[r]
//    (x8 fp32, broadcast LDS reads per lg).
//  - quad-mapped M rows: lane's 4 acc f32 = one 2x2 pool window -> fmax.
//  - output channel-permuted: lane packs 4 nt-bytes -> 1 dword store.
// LDS 11.5 KB.
// ---------------------------------------------------------------------------
__global__ __launch_bounds__(256, 4) void k_conv1_mfma(
    const float* __restrict__ x, const float* __restrict__ w1f,
    const float* __restrict__ b1, unsigned char* __restrict__ a1) {
    __shared__ u64 simg[960];     // [30][32] split records
    __shared__ float sxf[960];    // [30][32] fp32 padded image
    int b = blockIdx.x, tid = threadIdx.x;
    for (int i = tid; i < 960; i += 256) {
        int y = i >> 5, xc = i & 31;
        float v = 0.f;
        if (y >= 1 && y <= 28 && xc >= 1 && xc <= 28)
            v = x[(size_t)b * 784 + (y - 1) * 28 + (xc - 1)];
        sxf[i] = v;
        SPLIT3(v, h, m, lo);
        simg[i] = (u64)(h | (m << 16)) | ((u64)lo << 32);
    }
    int l = tid & 63, lr = l & 15, lg = l >> 4, w = tid >> 6;
    // lane's two taps
    int t0 = lg * 2, t1 = t0 + 1;
    int ky0 = (t0 * 21846) >> 16, kx0 = t0 - ky0 * 3;
    int ky1 = (t1 * 21846) >> 16, kx1 = t1 - ky1 * 3;
    int dt0 = (ky0 * 32 + kx0) * 8, dt1 = (ky1 * 32 + kx1) * 8;
    // B fragments (taps t0,t1 -> (s,s,s,0)), tap8 signs, bias
    v8s bf[4];
    float s8[4], b3[4];
#pragma unroll
    for (int nt = 0; nt < 4; ++nt) {
        const float* wr = w1f + (nt * 16 + lr) * 9;
        unsigned sa = (wr[t0] >= 0.f) ? 0x3F80u : 0xBF80u;
        unsigned sb = (wr[t1] >= 0.f) ? 0x3F80u : 0xBF80u;
        union { unsigned d[4]; v8s s; } u;
        u.d[0] = sa | (sa << 16); u.d[1] = sa;
        u.d[2] = sb | (sb << 16); u.d[3] = sb;
        bf[nt] = u.s;
        s8[nt] = (wr[8] >= 0.f) ? 1.f : -1.f;
        b3[nt] = 3.f * b1[nt * 16 + lr];
    }
    __syncthreads();

    const unsigned char* sib = (const unsigned char*)simg;
    unsigned char* outb = a1 + (size_t)b * 12544;
    for (int mt = w; mt < 49; mt += 4) {
        // A row = lr -> conv pixel
        int s = mt * 4 + (lr >> 2);
        int qy = (s * 4682) >> 16;            // /14
        int qx = s - qy * 14;
        int cy = 2 * qy + ((lr >> 1) & 1);
        int cx = 2 * qx + (lr & 1);
        int base = (cy * 32 + cx) * 8;
        u64 qa = *(const u64*)(sib + base + dt0);
        u64 qb = *(const u64*)(sib + base + dt1);
        v8s af = mk_v8s(qa, qb);
        v4f a0 = {0.f, 0.f, 0.f, 0.f}, a1v = {0.f, 0.f, 0.f, 0.f};
        v4f a2v = {0.f, 0.f, 0.f, 0.f}, a3v = {0.f, 0.f, 0.f, 0.f};
        a0  = __builtin_amdgcn_mfma_f32_16x16x32_bf16(af, bf[0], a0, 0, 0, 0);
        a1v = __builtin_amdgcn_mfma_f32_16x16x32_bf16(af, bf[1], a1v, 0, 0, 0);
        a2v = __builtin_amdgcn_mfma_f32_16x16x32_bf16(af, bf[2], a2v, 0, 0, 0);
        a3v = __builtin_amdgcn_mfma_f32_16x16x32_bf16(af, bf[3], a3v, 0, 0, 0);
        // tap8 (exact fp32): output quad q = mt*4+lg, member r=(dy,dx)
        int q = mt * 4 + lg;
        int Qy = (q * 4682) >> 16;
        int Qx = q - Qy * 14;
        const float* xr = &sxf[(2 * Qy + 2) * 32 + (2 * Qx + 2)];
        float x8_0 = xr[0], x8_1 = xr[1], x8_2 = xr[32], x8_3 = xr[33];
        unsigned dw;
        {
            float m0 = fmaxf(fmaxf(fmaf(s8[0], x8_0, a0[0]),  fmaf(s8[0], x8_1, a0[1])),
                             fmaxf(fmaf(s8[0], x8_2, a0[2]),  fmaf(s8[0], x8_3, a0[3])));
            float m1 = fmaxf(fmaxf(fmaf(s8[1], x8_0, a1v[0]), fmaf(s8[1], x8_1, a1v[1])),
                             fmaxf(fmaf(s8[1], x8_2, a1v[2]), fmaf(s8[1], x8_3, a1v[3])));
            float m2 = fmaxf(fmaxf(fmaf(s8[2], x8_0, a2v[0]), fmaf(s8[2], x8_1, a2v[1])),
                             fmaxf(fmaf(s8[2], x8_2, a2v[2]), fmaf(s8[2], x8_3, a2v[3])));
            float m3 = fmaxf(fmaxf(fmaf(s8[3], x8_0, a3v[0]), fmaf(s8[3], x8_1, a3v[1])),
                             fmaxf(fmaf(s8[3], x8_2, a3v[2]), fmaf(s8[3], x8_3, a3v[3])));
            dw  = quant3(fmaf(m0, 3.f, b3[0]));
            dw |= quant3(fmaf(m1, 3.f, b3[1])) << 8;
            dw |= quant3(fmaf(m2, 3.f, b3[2])) << 16;
            dw |= quant3(fmaf(m3, 3.f, b3[3])) << 24;
        }
        *(unsigned*)(outb + q * 64 + lr * 4) = dw;
    }
}

// ---------------------------------------------------------------------------
// conv2 via i8 MFMA, quad-mapped M-rows, linear staging + packed dword
// epilogue (channel-permuted; permutation baked into weights). (R9, unchanged)
// ---------------------------------------------------------------------------
__global__ __launch_bounds__(256, 3) void k_conv2_mfma(
    const unsigned char* __restrict__ a1, const char* __restrict__ w2p,
    const float* __restrict__ g1, const float* __restrict__ be1,
    const float* __restrict__ m1, const float* __restrict__ v1,
    unsigned char* __restrict__ a2) {
    __shared__ unsigned char sa[16384];      // [ck][16x16 padded pix][16]
    __shared__ char sw[36864];               // [t][ck][64 co][16]
    int b = blockIdx.x, tid = threadIdx.x;
    if (tid < 240) {
        int ck = tid & 3, e = tid >> 2;
        int py, px;
        if (e < 16)      { py = 0;      px = e; }
        else if (e < 32) { py = 15;     px = e - 16; }
        else if (e < 46) { py = e - 31; px = 0; }
        else             { py = e - 45; px = 15; }
        *(uint4*)(sa + ck * 4096 + (py * 16 + px) * 16) = make_uint4(0, 0, 0, 0);
    }
    {
        const uint4* src = (const uint4*)(a1 + (size_t)b * 12544);
        for (int i = tid; i < 784; i += 256) {
            int ck = i / 196, pixel = i - ck * 196;
            int py = pixel / 14, px = pixel - py * 14;
            *(uint4*)(sa + ck * 4096 + ((py + 1) * 16 + px + 1) * 16) =
                src[pixel * 4 + ck];
        }
        const uint4* wsrc = (const uint4*)w2p;
        uint4* wdst = (uint4*)sw;
        for (int i = tid; i < 2304; i += 256) wdst[i] = wsrc[i];
    }
    __syncthreads();

    int w = tid >> 6, l = tid & 63;
    int lr = l & 15, lg = l >> 4;
    int abase[4], mts[4];
#pragma unroll
    for (int j = 0; j < 4; ++j) {
        int mt = w + 4 * j;
        mts[j] = mt;
        int s = mt * 4 + (lr >> 2);
        if (s > 48) s = 48;
        int qy = s / 7, qx = s - qy * 7;
        int ty = 2 * qy + ((lr >> 1) & 1);
        int tx = 2 * qx + (lr & 1);
        abase[j] = lg * 4096 + (ty * 16 + tx) * 16;
    }
    v4i acc[4][4] = {};
#pragma unroll
    for (int t = 0; t < 9; ++t) {
        int ky = t / 3, kx = t - ky * 3;
        int boff = t * 4096 + lg * 1024 + lr * 16;
        v4i bfw[4];
#pragma unroll
        for (int nt = 0; nt < 4; ++nt)
            bfw[nt] = *(const v4i*)(sw + boff + nt * 256);
        int aoff = (ky * 16 + kx) * 16;
#pragma unroll
        for (int j = 0; j < 4; ++j) {
            if (mts[j] < 13) {
                v4i af = *(const v4i*)(sa + abase[j] + aoff);
#pragma unroll
                for (int nt = 0; nt < 4; ++nt)
                    acc[j][nt] = __builtin_amdgcn_mfma_i32_16x16x64_i8(
                        af, bfw[nt], acc[j][nt], 0, 0, 0);
            }
        }
    }

    float sc4[4], of4[4];
#pragma unroll
    for (int nt = 0; nt < 4; ++nt) {
        int ch = nt * 16 + lr;
        float si = g1[ch] * rsqrtf(v1[ch] + 1e-4f);
        sc4[nt] = si;
        of4[nt] = 3.f * (be1[ch] - m1[ch] * si);
    }
#pragma unroll
    for (int j = 0; j < 4; ++j) {
        int q = mts[j] * 4 + lg;
        if (q < 49) {
            unsigned dw = 0;
#pragma unroll
            for (int nt = 0; nt < 4; ++nt) {
                int mx = imax(imax(acc[j][nt][0], acc[j][nt][1]),
                              imax(acc[j][nt][2], acc[j][nt][3]));
                int mn = imin(imin(acc[j][nt][0], acc[j][nt][1]),
                              imin(acc[j][nt][2], acc[j][nt][3]));
                float sc = sc4[nt];
                int v = (sc >= 0.f) ? mx : mn;
                dw |= quant3(fmaf((float)v, sc, of4[nt])) << (8 * nt);
            }
            *(unsigned*)(a2 + (size_t)b * 3136 + q * 64 + lr * 4) = dw;
        }
    }
}

// ---------------------------------------------------------------------------
// conv3 via i8 MFMA: 4 images/block; packed dword epilogue. (R9, unchanged)
// ---------------------------------------------------------------------------
__global__ __launch_bounds__(256, 2) void k_conv3_mfma(
    const unsigned char* __restrict__ a2, const char* __restrict__ w3p,
    const float* __restrict__ g2, const float* __restrict__ be2,
    const float* __restrict__ m2, const float* __restrict__ v2,
    unsigned char* __restrict__ a3) {
    __shared__ unsigned char sa[4 * 3136];   // [img][ck][49][16]
    __shared__ char sw[36864];               // [t][ck][64 co][16]
    __shared__ unsigned char so[4 * 2560];   // [img][32 pix][80]
    int b0 = blockIdx.x * 4, tid = threadIdx.x;
    {
        const uint4* src = (const uint4*)(a2 + (size_t)b0 * 3136);
        for (int i = tid; i < 784; i += 256) {
            int img = i / 196, r = i - img * 196;
            int ck = r / 49, pixel = r - ck * 49;
            *(uint4*)(sa + img * 3136 + ck * 784 + pixel * 16) =
                src[img * 196 + pixel * 4 + ck];
        }
        const uint4* wsrc = (const uint4*)w3p;
        uint4* wdst = (uint4*)sw;
        for (int i = tid; i < 2304; i += 256) wdst[i] = wsrc[i];
    }
    __syncthreads();

    int w = tid >> 6, l = tid & 63;
    int lr = l & 15, lg = l >> 4;
    const unsigned char* sai = sa + w * 3136;
    int abase[2];
#pragma unroll
    for (int mt = 0; mt < 2; ++mt) {
        int p = mt * 16 + lr;
        if (p > 24) p = 24;
        int oy = p / 5, ox = p - oy * 5;
        abase[mt] = lg * 784 + (oy * 7 + ox) * 16;
    }
    v4i acc[2][4] = {};
#pragma unroll
    for (int t = 0; t < 9; ++t) {
        int ky = t / 3, kx = t - ky * 3;
        int boff = t * 4096 + lg * 1024 + lr * 16;
        v4i bfw[4];
#pragma unroll
        for (int nt = 0; nt < 4; ++nt)
            bfw[nt] = *(const v4i*)(sw + boff + nt * 256);
        int aoff = (ky * 7 + kx) * 16;
#pragma unroll
        for (int mt = 0; mt < 2; ++mt) {
            v4i af = *(const v4i*)(sai + abase[mt] + aoff);
#pragma unroll
            for (int nt = 0; nt < 4; ++nt)
                acc[mt][nt] = __builtin_amdgcn_mfma_i32_16x16x64_i8(
                    af, bfw[nt], acc[mt][nt], 0, 0, 0);
        }
    }

    float sc4[4], of4[4];
#pragma unroll
    for (int nt = 0; nt < 4; ++nt) {
        int ch = nt * 16 + lr;
        float si = g2[ch] * rsqrtf(v2[ch] + 1e-4f);
        sc4[nt] = si;
        of4[nt] = 3.f * (be2[ch] - m2[ch] * si);
    }
    unsigned char* soi = so + w * 2560;
#pragma unroll
    for (int mt = 0; mt < 2; ++mt)
#pragma unroll
        for (int r = 0; r < 4; ++r) {
            int pixel = mt * 16 + lg * 4 + r;
            unsigned dw = 0;
#pragma unroll
            for (int nt = 0; nt < 4; ++nt)
                dw |= quant3(fmaf((float)acc[mt][nt][r], sc4[nt], of4[nt])) << (8 * nt);
            *(unsigned*)(soi + pixel * 80 + lr * 4) = dw;
        }
    __syncthreads();
    for (int idx = tid; idx < 400; idx += 256) {
        int img = idx / 100, r = idx - img * 100;
        int p = r >> 2, c0 = r & 3;
        *(uint4*)(a3 + (size_t)(b0 + img) * 1600 + r * 16) =
            *(const uint4*)(so + img * 2560 + p * 80 + c0 * 16);
    }
}

// ---------------------------------------------------------------------------
// fc1 via i8 MFMA (unchanged; fw1s columns pre-permuted to match a3)
// ---------------------------------------------------------------------------
__global__ __launch_bounds__(256) void k_fc1_mfma(
    const unsigned char* __restrict__ a3, const char* __restrict__ fw1s,
    const float* __restrict__ fb1, float* __restrict__ h1) {
    __shared__ unsigned char sA[64 * 80];
    __shared__ unsigned char sB[64 * 80];
    __shared__ float sbias[64];
    int bb = (blockIdx.x >> 3) * 64;
    int ob = (blockIdx.x & 7) * 64;
    int tid = threadIdx.x;
    int row = tid >> 2, seg = tid & 3;
    if (tid < 64) sbias[tid] = fb1[ob + tid];
    const unsigned char* Ag = a3 + (size_t)(bb + row) * 1600 + seg * 16;
    const char* Bg = fw1s + (size_t)(ob + row) * 1600 + seg * 16;
    uint4 av = *(const uint4*)Ag;
    uint4 bv = *(const uint4*)Bg;

    int w = tid >> 6, l = tid & 63;
    int wm = w >> 1, wn = w & 1;
    int lr = l & 15, lg = l >> 4;
    const unsigned char* sAr = sA + (wm * 32 + lr) * 80 + lg * 16;
    const unsigned char* sBr = sB + (wn * 32 + lr) * 80 + lg * 16;
    v4i acc[2][2] = {};

    for (int k0 = 0; k0 < 1600; k0 += 64) {
        *(uint4*)(sA + row * 80 + seg * 16) = av;
        *(uint4*)(sB + row * 80 + seg * 16) = bv;
        __syncthreads();
        if (k0 < 1536) {
            av = *(const uint4*)(Ag + k0 + 64);
            bv = *(const uint4*)(Bg + k0 + 64);
        }
        v4i af0 = *(const v4i*)(sAr);
        v4i af1 = *(const v4i*)(sAr + 16 * 80);
        v4i bf0 = *(const v4i*)(sBr);
        v4i bf1 = *(const v4i*)(sBr + 16 * 80);
        acc[0][0] = __builtin_amdgcn_mfma_i32_16x16x64_i8(af0, bf0, acc[0][0], 0, 0, 0);
        acc[0][1] = __builtin_amdgcn_mfma_i32_16x16x64_i8(af0, bf1, acc[0][1], 0, 0, 0);
        acc[1][0] = __builtin_amdgcn_mfma_i32_16x16x64_i8(af1, bf0, acc[1][0], 0, 0, 0);
        acc[1][1] = __builtin_amdgcn_mfma_i32_16x16x64_i8(af1, bf1, acc[1][1], 0, 0, 0);
        __syncthreads();
    }

    const float inv3 = 1.f / 3.f;
#pragma unroll
    for (int mt = 0; mt < 2; ++mt)
#pragma unroll
        for (int nt = 0; nt < 2; ++nt) {
            int gcol = ob + wn * 32 + nt * 16 + lr;
            float bias = sbias[wn * 32 + nt * 16 + lr];
#pragma unroll
            for (int r = 0; r < 4; ++r) {
                int grow = bb + wm * 32 + mt * 16 + lg * 4 + r;
                h1[(size_t)grow * 512 + gcol] = (float)acc[mt][nt][r] * inv3 + bias;
            }
        }
}

// ---------------------------------------------------------------------------
// fc2 + log_softmax (unchanged)
// ---------------------------------------------------------------------------
__global__ __launch_bounds__(256) void k_fc2(
    const float* __restrict__ h1, const float* __restrict__ fw2,
    const float* __restrict__ fb2, float* __restrict__ out) {
    __shared__ float sw[5120];
    __shared__ float sb[16];
    int tid = threadIdx.x;
    for (int i = tid; i < 5120; i += 256) sw[i] = fw2[i];
    if (tid < 10) sb[tid] = fb2[tid];
    __syncthreads();

    int wv = tid >> 6, lane = tid & 63;
    int b = blockIdx.x * 4 + wv;
    const float* hr = h1 + (size_t)b * 512;
    float p[10];
#pragma unroll
    for (int o = 0; o < 10; ++o) p[o] = 0.f;
    for (int k = lane; k < 512; k += 64) {
        float hv = hr[k];
#pragma unroll
        for (int o = 0; o < 10; ++o) p[o] += hv * sw[o * 512 + k];
    }
#pragma unroll
    for (int o = 0; o < 10; ++o) {
#pragma unroll
        for (int off = 32; off > 0; off >>= 1) p[o] += __shfl_xor(p[o], off, 64);
        p[o] += sb[o];
    }
    float mx = p[0];
#pragma unroll
    for (int o = 1; o < 10; ++o) mx = fmaxf(mx, p[o]);
    float se = 0.f;
#pragma unroll
    for (int o = 0; o < 10; ++o) se += expf(p[o] - mx);
    float lse = logf(se) + mx;
    float myv = 0.f;
#pragma unroll
    for (int o = 0; o < 10; ++o) myv = (lane == o) ? p[o] : myv;
    if (lane < 10) out[(size_t)b * 10 + lane] = myv - lse;
}

// ---------------------------------------------------------------------------
extern "C" void kernel_launch(void* const* d_in, const int* in_sizes, int n_in,
                              void* d_out, int out_size, void* d_ws, size_t ws_size,
                              hipStream_t stream) {
    const float* x   = (const float*)d_in[0];
    const float* w1  = (const float*)d_in[1];
    const float* b1  = (const float*)d_in[2];
    const float* w2  = (const float*)d_in[3];
    const float* g1  = (const float*)d_in[4];
    const float* be1 = (const float*)d_in[5];
    const float* m1  = (const float*)d_in[6];
    const float* v1  = (const float*)d_in[7];
    const float* w3  = (const float*)d_in[8];
    const float* g2  = (const float*)d_in[9];
    const float* be2 = (const float*)d_in[10];
    const float* m2  = (const float*)d_in[11];
    const float* v2  = (const float*)d_in[12];
    const float* fw1 = (const float*)d_in[13];
    const float* fb1 = (const float*)d_in[14];
    const float* fw2 = (const float*)d_in[15];
    const float* fb2 = (const float*)d_in[16];
    float* out = (float*)d_out;

    char* ws = (char*)d_ws;
    char* w2p  = ws;                                   // 36864
    char* w3p  = ws + 36864;                           // 36864
    char* fw1s = ws + 73728;                           // 819200
    unsigned char* a1 = (unsigned char*)(ws + 892928); // 4096*12544 = 51380224
    unsigned char* a2 = a1 + 51380224;                 // 4096*3136  = 12845056
    unsigned char* a3 = a2 + 12845056;                 // 4096*1600  = 6553600
    float* h1 = (float*)(void*)a1;                     // alias: a1 dead when fc1 runs

    k_signs<<<3200, 256, 0, stream>>>(w2, w3, fw1, w2p, w3p, fw1s);
    k_conv1_mfma<<<4096, 256, 0, stream>>>(x, w1, b1, a1);
    k_conv2_mfma<<<4096, 256, 0, stream>>>(a1, w2p, g1, be1, m1, v1, a2);
    k_conv3_mfma<<<1024, 256, 0, stream>>>(a2, w3p, g2, be2, m2, v2, a3);
    k_fc1_mfma<<<512, 256, 0, stream>>>(a3, fw1s, fb1, h1);
    k_fc2<<<1024, 256, 0, stream>>>(h1, fw2, fb2, out);
}